// Round 1
// baseline (942.664 us; speedup 1.0000x reference)
//
#include <hip/hip_runtime.h>
#include <hip/hip_bf16.h>
#include <stdint.h>

#define DM   1024
#define SJ   4608
#define SCTX 512
#define SIMG 4096
#define NCH  512
#define TCH  9

typedef __attribute__((ext_vector_type(8))) short bf16x8;
typedef __attribute__((ext_vector_type(4))) float f32x4;

__device__ __forceinline__ float bf2f(unsigned short u){
  union { unsigned int i; float f; } v; v.i = ((unsigned int)u) << 16; return v.f;
}
// round-to-nearest-even f32 -> bf16 (bit trick; no NaNs in this workload)
__device__ __forceinline__ unsigned short f2bf(float f){
  unsigned int u = __float_as_uint(f);
  u += 0x7fffu + ((u >> 16) & 1u);
  return (unsigned short)(u >> 16);
}
__device__ __forceinline__ float sigm(float x){ return 1.f/(1.f+__expf(-x)); }

__device__ __forceinline__ float wsum(float v){
  #pragma unroll
  for(int o=32;o>0;o>>=1) v += __shfl_xor(v,o);
  return v;
}
__device__ __forceinline__ float wmax(float v){
  #pragma unroll
  for(int o=32;o>0;o>>=1) v = fmaxf(v,__shfl_xor(v,o));
  return v;
}
__device__ __forceinline__ void blockSumSum(float& a, float& b, float* s1, float* s2){
  a = wsum(a); b = wsum(b);
  if(!(threadIdx.x&63)){ s1[threadIdx.x>>6]=a; s2[threadIdx.x>>6]=b; }
  __syncthreads();
  a = s1[0]+s1[1]+s1[2]+s1[3];
  b = s2[0]+s2[1]+s2[2]+s2[3];
  __syncthreads();
}
__device__ __forceinline__ void blockSumMax(float& a, float& b, float* s1, float* s2){
  a = wsum(a); b = wmax(b);
  if(!(threadIdx.x&63)){ s1[threadIdx.x>>6]=a; s2[threadIdx.x>>6]=b; }
  __syncthreads();
  a = s1[0]+s1[1]+s1[2]+s1[3];
  b = fmaxf(fmaxf(s2[0],s2[1]),fmaxf(s2[2],s2[3]));
  __syncthreads();
}

// ---------------- async global->LDS ----------------
typedef __attribute__((address_space(1))) void gvoid_t;
typedef __attribute__((address_space(3))) void lvoid_t;
__device__ __forceinline__ void gl_lds16(const void* g, void* l){
  __builtin_amdgcn_global_load_lds((gvoid_t*)g, (lvoid_t*)l, 16, 0, 0);
}

// ---------------- weight quantization ----------------
struct WList {
  const float* w[8];
  unsigned long long n[8];
  unsigned short* q[8];
};

__global__ __launch_bounds__(256)
void wq_reduce(WList L, float* __restrict__ part){
  __shared__ float s1[4];
  int m = blockIdx.y;
  const float4* w4 = (const float4*)L.w[m];
  size_t n4 = L.n[m] >> 2;
  float s = 0.f;
  for(size_t i = (size_t)blockIdx.x*256 + threadIdx.x; i < n4; i += (size_t)512*256){
    float4 v = w4[i];
    s += fabsf(v.x)+fabsf(v.y)+fabsf(v.z)+fabsf(v.w);
  }
  s = wsum(s);
  if(!(threadIdx.x&63)) s1[threadIdx.x>>6] = s;
  __syncthreads();
  if(!threadIdx.x) part[m*512 + blockIdx.x] = s1[0]+s1[1]+s1[2]+s1[3];
}

__global__ __launch_bounds__(256)
void wq_finalize(WList L, const float* __restrict__ part, float* __restrict__ swinv){
  __shared__ float s1[4];
  int m = blockIdx.x;
  float s = part[m*512 + threadIdx.x] + part[m*512 + 256 + threadIdx.x];
  s = wsum(s);
  if(!(threadIdx.x&63)) s1[threadIdx.x>>6] = s;
  __syncthreads();
  if(!threadIdx.x){
    float mean = (s1[0]+s1[1]+s1[2]+s1[3]) / (float)L.n[m];
    swinv[m] = fmaxf(mean, 1e-5f);   // dequant factor = clip(mean|w|,1e-5)
  }
}

__global__ __launch_bounds__(256)
void wq_quant(WList L, const float* __restrict__ swinv){
  int m = blockIdx.y;
  float sc = 1.f / swinv[m];
  const float4* w4 = (const float4*)L.w[m];
  unsigned short* q = L.q[m];
  size_t n4 = L.n[m] >> 2;
  for(size_t i = (size_t)blockIdx.x*256 + threadIdx.x; i < n4; i += (size_t)1024*256){
    float4 v = w4[i];
    ushort4 o;
    o.x = f2bf(fminf(fmaxf(rintf(v.x*sc),-1.f),1.f));
    o.y = f2bf(fminf(fmaxf(rintf(v.y*sc),-1.f),1.f));
    o.z = f2bf(fminf(fmaxf(rintf(v.z*sc),-1.f),1.f));
    o.w = f2bf(fminf(fmaxf(rintf(v.w*sc),-1.f),1.f));
    ((ushort4*)q)[i] = o;
  }
}

// ---------------- adaLN embedding GEMV: e = silu(temb) @ W^T + b ----------------
__global__ __launch_bounds__(256)
void adaln_gemv(const float* __restrict__ temb, const float* __restrict__ W,
                const float* __restrict__ bias, float* __restrict__ e){
  int o = blockIdx.x*4 + (threadIdx.x>>6);
  int b = blockIdx.y;
  int lane = threadIdx.x & 63;
  const float4* t4 = (const float4*)(temb + b*DM);
  const float4* w4 = (const float4*)(W + (size_t)o*DM);
  float acc = 0.f;
  #pragma unroll
  for(int i=0;i<4;i++){
    float4 tv = t4[i*64+lane], wv = w4[i*64+lane];
    acc += (tv.x*sigm(tv.x))*wv.x + (tv.y*sigm(tv.y))*wv.y
         + (tv.z*sigm(tv.z))*wv.z + (tv.w*sigm(tv.w))*wv.w;
  }
  acc = wsum(acc);
  if(!lane) e[b*6144 + o] = acc + bias[o];
}

// ---------------- LN -> adaLN modulate -> rmsnorm -> act_quant ----------------
__global__ __launch_bounds__(256)
void modnorm_quant(const float* __restrict__ x, int bshift,
                   const float* __restrict__ e, int scaleOff, int shiftOff,
                   unsigned short* __restrict__ xq, float* __restrict__ rsx,
                   int outRowOff, int outBatchStride){
  __shared__ float s1[4], s2[4];
  const int tid = threadIdx.x;
  const int row = blockIdx.x;
  const int b = row >> bshift, s = row & ((1<<bshift)-1);
  float4 xv = ((const float4*)(x + (size_t)row*DM))[tid];
  float sum = xv.x+xv.y+xv.z+xv.w;
  float ss  = xv.x*xv.x+xv.y*xv.y+xv.z*xv.z+xv.w*xv.w;
  blockSumSum(sum, ss, s1, s2);
  float mu  = sum * (1.f/DM);
  float inv = rsqrtf(ss*(1.f/DM) - mu*mu + 1e-6f);
  float4 scv = ((const float4*)(e + b*6144 + scaleOff))[tid];
  float4 shv = ((const float4*)(e + b*6144 + shiftOff))[tid];
  float n0 = (xv.x-mu)*inv*(1.f+scv.x)+shv.x;
  float n1 = (xv.y-mu)*inv*(1.f+scv.y)+shv.y;
  float n2 = (xv.z-mu)*inv*(1.f+scv.z)+shv.z;
  float n3 = (xv.w-mu)*inv*(1.f+scv.w)+shv.w;
  float ss2 = n0*n0+n1*n1+n2*n2+n3*n3;
  float mx  = fmaxf(fmaxf(fabsf(n0),fabsf(n1)),fmaxf(fabsf(n2),fabsf(n3)));
  blockSumMax(ss2, mx, s1, s2);
  float rms   = rsqrtf(ss2*(1.f/DM) + 1e-6f);
  float amaxn = fmaxf(mx*rms, 1e-5f);
  float k     = rms*127.f/amaxn;
  int orow = b*outBatchStride + outRowOff + s;
  ushort4 q;
  q.x = f2bf(fminf(fmaxf(rintf(n0*k),-128.f),127.f));
  q.y = f2bf(fminf(fmaxf(rintf(n1*k),-128.f),127.f));
  q.z = f2bf(fminf(fmaxf(rintf(n2*k),-128.f),127.f));
  q.w = f2bf(fminf(fmaxf(rintf(n3*k),-128.f),127.f));
  ((ushort4*)(xq + (size_t)orow*DM))[tid] = q;
  if(!tid) rsx[orow] = amaxn*(1.f/127.f);
}

// ---------------- rmsnorm(o)*gnw*silu(g) -> rmsnorm -> act_quant ----------------
__global__ __launch_bounds__(256)
void gnorm_quant(const unsigned short* __restrict__ o, const unsigned short* __restrict__ g,
                 const float* __restrict__ gnw,
                 unsigned short* __restrict__ xq, float* __restrict__ rsx){
  __shared__ float s1[4], s2[4];
  const int tid = threadIdx.x;
  const size_t row = blockIdx.x;
  ushort4 ov = ((const ushort4*)(o + row*DM))[tid];
  ushort4 gv = ((const ushort4*)(g + row*DM))[tid];
  float o0=bf2f(ov.x), o1=bf2f(ov.y), o2=bf2f(ov.z), o3=bf2f(ov.w);
  float g0=bf2f(gv.x), g1=bf2f(gv.y), g2=bf2f(gv.z), g3=bf2f(gv.w);
  float ss = o0*o0+o1*o1+o2*o2+o3*o3;
  float dummy = 0.f;
  blockSumSum(ss, dummy, s1, s2);
  float rms = rsqrtf(ss*(1.f/DM) + 1e-6f);
  float4 wv = ((const float4*)gnw)[tid];
  float n0 = o0*rms*wv.x*(g0*sigm(g0));
  float n1 = o1*rms*wv.y*(g1*sigm(g1));
  float n2 = o2*rms*wv.z*(g2*sigm(g2));
  float n3 = o3*rms*wv.w*(g3*sigm(g3));
  float ss2 = n0*n0+n1*n1+n2*n2+n3*n3;
  float mx  = fmaxf(fmaxf(fabsf(n0),fabsf(n1)),fmaxf(fabsf(n2),fabsf(n3)));
  blockSumMax(ss2, mx, s1, s2);
  float rms2  = rsqrtf(ss2*(1.f/DM) + 1e-6f);
  float amaxn = fmaxf(mx*rms2, 1e-5f);
  float k     = rms2*127.f/amaxn;
  ushort4 q;
  q.x = f2bf(fminf(fmaxf(rintf(n0*k),-128.f),127.f));
  q.y = f2bf(fminf(fmaxf(rintf(n1*k),-128.f),127.f));
  q.z = f2bf(fminf(fmaxf(rintf(n2*k),-128.f),127.f));
  q.w = f2bf(fminf(fmaxf(rintf(n3*k),-128.f),127.f));
  ((ushort4*)(xq + row*DM))[tid] = q;
  if(!tid) rsx[row] = amaxn*(1.f/127.f);
}

// ---------------- rmsnorm -> act_quant, in-place, D=4096 bf16 rows ----------------
__global__ __launch_bounds__(256)
void rmsq4096(unsigned short* __restrict__ z, float* __restrict__ rsx){
  __shared__ float s1[4], s2[4];
  const int tid = threadIdx.x;
  unsigned short* zr = z + (size_t)blockIdx.x*4096;
  float v[16];
  #pragma unroll
  for(int i=0;i<4;i++){
    ushort4 u = ((const ushort4*)zr)[tid + i*256];
    v[i*4+0]=bf2f(u.x); v[i*4+1]=bf2f(u.y); v[i*4+2]=bf2f(u.z); v[i*4+3]=bf2f(u.w);
  }
  float ss=0.f, mx=0.f;
  #pragma unroll
  for(int i=0;i<16;i++){ ss += v[i]*v[i]; mx = fmaxf(mx, fabsf(v[i])); }
  blockSumMax(ss, mx, s1, s2);
  float rms   = rsqrtf(ss*(1.f/4096.f) + 1e-6f);
  float amaxn = fmaxf(mx*rms, 1e-5f);
  float k     = rms*127.f/amaxn;
  #pragma unroll
  for(int i=0;i<4;i++){
    ushort4 q;
    q.x = f2bf(fminf(fmaxf(rintf(v[i*4+0]*k),-128.f),127.f));
    q.y = f2bf(fminf(fmaxf(rintf(v[i*4+1]*k),-128.f),127.f));
    q.z = f2bf(fminf(fmaxf(rintf(v[i*4+2]*k),-128.f),127.f));
    q.w = f2bf(fminf(fmaxf(rintf(v[i*4+3]*k),-128.f),127.f));
    ((ushort4*)zr)[tid + i*256] = q;
  }
  if(!tid) rsx[blockIdx.x] = amaxn*(1.f/127.f);
}

// ---------------- HGRN chunked scan ----------------
__global__ __launch_bounds__(256)
void scan_pass1(const unsigned short* __restrict__ ir, const unsigned short* __restrict__ fr,
                float* __restrict__ A, float* __restrict__ B){
  int c = blockIdx.x, b = blockIdx.y;
  int d0 = threadIdx.x*4;
  size_t base = ((size_t)b*SJ + (size_t)c*TCH)*DM + d0;
  float a0=1,a1=1,a2=1,a3=1, h0=0,h1=0,h2=0,h3=0;
  #pragma unroll
  for(int t=0;t<TCH;t++){
    ushort4 iv = *(const ushort4*)(ir + base + (size_t)t*DM);
    ushort4 fv = *(const ushort4*)(fr + base + (size_t)t*DM);
    float f0=sigm(bf2f(fv.x)), f1=sigm(bf2f(fv.y)), f2=sigm(bf2f(fv.z)), f3=sigm(bf2f(fv.w));
    float x0=bf2f(iv.x), x1=bf2f(iv.y), x2=bf2f(iv.z), x3=bf2f(iv.w);
    float p0=x0*sigm(x0)*(1.f-f0), p1=x1*sigm(x1)*(1.f-f1);
    float p2=x2*sigm(x2)*(1.f-f2), p3=x3*sigm(x3)*(1.f-f3);
    h0=f0*h0+p0; h1=f1*h1+p1; h2=f2*h2+p2; h3=f3*h3+p3;
    a0*=f0; a1*=f1; a2*=f2; a3*=f3;
  }
  size_t idx = (size_t)c*2048 + b*1024 + d0;
  *(float4*)(A + idx) = make_float4(a0,a1,a2,a3);
  *(float4*)(B + idx) = make_float4(h0,h1,h2,h3);
}

__global__ __launch_bounds__(256)
void scan_pass2(const float* __restrict__ A, const float* __restrict__ B, float* __restrict__ H){
  int chain = blockIdx.x*256 + threadIdx.x;  // 2048 chains
  float h = 0.f;
  for(int c0=0;c0<NCH;c0+=8){
    float a[8], bb[8];
    #pragma unroll
    for(int u=0;u<8;u++){
      a[u]  = A[(size_t)(c0+u)*2048 + chain];
      bb[u] = B[(size_t)(c0+u)*2048 + chain];
    }
    #pragma unroll
    for(int u=0;u<8;u++){
      H[(size_t)(c0+u)*2048 + chain] = h;
      h = a[u]*h + bb[u];
    }
  }
}

__global__ __launch_bounds__(256)
void scan_pass3(const unsigned short* __restrict__ ir, const unsigned short* __restrict__ fr,
                const float* __restrict__ H, unsigned short* __restrict__ o){
  int c = blockIdx.x, b = blockIdx.y;
  int d0 = threadIdx.x*4;
  size_t base = ((size_t)b*SJ + (size_t)c*TCH)*DM + d0;
  float4 hv = *(const float4*)(H + (size_t)c*2048 + b*1024 + d0);
  float h0=hv.x, h1=hv.y, h2=hv.z, h3=hv.w;
  #pragma unroll
  for(int t=0;t<TCH;t++){
    ushort4 iv = *(const ushort4*)(ir + base + (size_t)t*DM);
    ushort4 fv = *(const ushort4*)(fr + base + (size_t)t*DM);
    float f0=sigm(bf2f(fv.x)), f1=sigm(bf2f(fv.y)), f2=sigm(bf2f(fv.z)), f3=sigm(bf2f(fv.w));
    float x0=bf2f(iv.x), x1=bf2f(iv.y), x2=bf2f(iv.z), x3=bf2f(iv.w);
    float p0=x0*sigm(x0)*(1.f-f0), p1=x1*sigm(x1)*(1.f-f1);
    float p2=x2*sigm(x2)*(1.f-f2), p3=x3*sigm(x3)*(1.f-f3);
    h0=f0*h0+p0; h1=f1*h1+p1; h2=f2*h2+p2; h3=f3*h3+p3;
    ushort4 ov; ov.x=f2bf(h0); ov.y=f2bf(h1); ov.z=f2bf(h2); ov.w=f2bf(h3);
    *(ushort4*)(o + base + (size_t)t*DM) = ov;
  }
}

// ---------------- bf16 MFMA GEMM, B^T layout, templated epilogue ----------------
#define EPI_BF16  0
#define EPI_WO    1
#define EPI_SILU  2
#define EPI_MUL   3
#define EPI_RESID 4

struct GemmP {
  const float* rsx;      // per-row act dequant
  const float* swinv;    // weight dequant (1 float)
  unsigned short* outb;  // bf16 output
  float* outf;           // f32 output
  const float* resid;    // RESID base
  const float* egate;    // RESID gate table (chunk 5)
  int bshift;            // RESID log2(rows/batch)
  const float* eh; const float* ec;      // WO gates (chunk 2)
  const float* hid; const float* enc;    // WO residual bases
  float* out_h; float* out_c;            // WO outputs
};

template<int EPI>
__global__ __launch_bounds__(256)
void gemm_bt(const unsigned short* __restrict__ Aq, const unsigned short* __restrict__ Wq,
             int M, int N, int K, GemmP p){
  __shared__ unsigned short As[128*32];
  __shared__ unsigned short Bs[128*32];
  const int tid = threadIdx.x;
  const int wave = tid>>6, lane = tid&63;
  const int nb = blockIdx.x, mb = blockIdx.y;
  const int wr = wave>>1, wc = wave&1;

  const int srow = wave*16 + (lane>>2);
  const int scol = (lane&3)*8;
  const unsigned short* a0 = Aq + (size_t)(mb*128 + srow)*K + scol;
  const unsigned short* a1 = a0 + (size_t)64*K;
  const unsigned short* b0 = Wq + (size_t)(nb*128 + srow)*K + scol;
  const unsigned short* b1 = b0 + (size_t)64*K;
  char* asb = (char*)As + wave*1024;
  char* bsb = (char*)Bs + wave*1024;

  f32x4 acc[4][4];
  #pragma unroll
  for(int i=0;i<4;i++)
    #pragma unroll
    for(int j=0;j<4;j++) acc[i][j] = (f32x4){0.f,0.f,0.f,0.f};

  const int lrow = lane&15, lk = (lane>>4)*8;
  const unsigned short* arow = &As[(wr*64 + lrow)*32 + lk];
  const unsigned short* brow = &Bs[(wc*64 + lrow)*32 + lk];

  for(int k0=0; k0<K; k0+=32){
    gl_lds16(a0 + k0, asb);
    gl_lds16(a1 + k0, asb + 4096);
    gl_lds16(b0 + k0, bsb);
    gl_lds16(b1 + k0, bsb + 4096);
    __syncthreads();
    bf16x8 af[4], bfr[4];
    #pragma unroll
    for(int m=0;m<4;m++) af[m]  = *(const bf16x8*)(arow + m*512);
    #pragma unroll
    for(int n=0;n<4;n++) bfr[n] = *(const bf16x8*)(brow + n*512);
    #pragma unroll
    for(int m=0;m<4;m++)
      #pragma unroll
      for(int n=0;n<4;n++)
        acc[m][n] = __builtin_amdgcn_mfma_f32_16x16x32_bf16(af[m], bfr[n], acc[m][n], 0,0,0);
    __syncthreads();
  }

  const float sw = *p.swinv;
  const int r0 = mb*128 + wr*64, c0 = nb*128 + wc*64;
  #pragma unroll
  for(int m=0;m<4;m++){
    #pragma unroll
    for(int j=0;j<4;j++){
      int r = r0 + m*16 + ((lane>>4)<<2) + j;
      float rs = p.rsx[r]*sw;
      #pragma unroll
      for(int n=0;n<4;n++){
        int c = c0 + n*16 + (lane&15);
        float val = acc[m][n][j]*rs;
        if constexpr (EPI==EPI_BF16){
          p.outb[(size_t)r*N + c] = f2bf(val);
        } else if constexpr (EPI==EPI_SILU){
          p.outb[(size_t)r*N + c] = f2bf(val*sigm(val));
        } else if constexpr (EPI==EPI_MUL){
          size_t idx = (size_t)r*N + c;
          p.outb[idx] = f2bf(bf2f(p.outb[idx])*val);
        } else if constexpr (EPI==EPI_RESID){
          int b = r >> p.bshift;
          size_t idx = (size_t)r*DM + c;
          p.outf[idx] = p.resid[idx] + p.egate[b*6144 + 5*1024 + c]*val;
        } else { // EPI_WO
          int b = r / SJ; int s = r - b*SJ;
          if (s < SCTX){
            size_t idx = ((size_t)b*SCTX + s)*DM + c;
            p.out_c[idx] = p.enc[idx] + p.ec[b*6144 + 2*1024 + c]*val;
          } else {
            size_t idx = ((size_t)b*SIMG + (s-SCTX))*DM + c;
            p.out_h[idx] = p.hid[idx] + p.eh[b*6144 + 2*1024 + c]*val;
          }
        }
      }
    }
  }
}

// ================= host =================
extern "C" void kernel_launch(void* const* d_in, const int* in_sizes, int n_in,
                              void* d_out, int out_size, void* d_ws, size_t ws_size,
                              hipStream_t stream){
  (void)in_sizes; (void)n_in; (void)out_size; (void)ws_size;
  const float* hidden   = (const float*)d_in[0];
  const float* enc      = (const float*)d_in[1];
  const float* temb     = (const float*)d_in[2];
  const float* adaln_w  = (const float*)d_in[3];
  const float* adaln_b  = (const float*)d_in[4];
  const float* adaln_cw = (const float*)d_in[5];
  const float* adaln_cb = (const float*)d_in[6];
  const float* wi  = (const float*)d_in[7];
  const float* wf  = (const float*)d_in[8];
  const float* wg  = (const float*)d_in[9];
  const float* wo  = (const float*)d_in[10];
  const float* gnw = (const float*)d_in[11];
  const float* ffg = (const float*)d_in[12];
  const float* ffd = (const float*)d_in[13];
  const float* fcg = (const float*)d_in[14];
  const float* fcd = (const float*)d_in[15];

  const size_t MB = 1024ull*1024ull;
  char* ws = (char*)d_ws;
  unsigned short* WQ_WI  = (unsigned short*)(ws + 0*MB);
  unsigned short* WQ_WF  = (unsigned short*)(ws + 2*MB);
  unsigned short* WQ_WG  = (unsigned short*)(ws + 4*MB);
  unsigned short* WQ_WO  = (unsigned short*)(ws + 6*MB);
  unsigned short* WQ_FFG = (unsigned short*)(ws + 8*MB);
  unsigned short* WQ_FFD = (unsigned short*)(ws + 24*MB);
  unsigned short* WQ_FCG = (unsigned short*)(ws + 32*MB);
  unsigned short* WQ_FCD = (unsigned short*)(ws + 48*MB);
  float* PART  = (float*)(ws + 56*MB);
  float* SWINV = (float*)(ws + 56*MB + 32*1024);
  float* EH    = (float*)(ws + 56*MB + 64*1024);
  float* EC    = (float*)(ws + 56*MB + 112*1024);
  float* RSX1  = (float*)(ws + 56*MB + 160*1024);
  float* RSX2  = (float*)(ws + 56*MB + 200*1024);
  float* RSX3  = (float*)(ws + 56*MB + 240*1024);
  float* RSXZ  = (float*)(ws + 56*MB + 280*1024);
  float* RSX4  = (float*)(ws + 56*MB + 320*1024);
  float* RSXZC = (float*)(ws + 56*MB + 328*1024);
  float* SCANA = (float*)(ws + 57*MB);   // 4MB
  float* SCANB = (float*)(ws + 61*MB);   // 4MB
  float* SCANH = (float*)(ws + 65*MB);   // 4MB
  unsigned short* XQ   = (unsigned short*)(ws + 70*MB);   // 18.9MB (xq_joint/xq2/nh2q/nc2q)
  unsigned short* IRAW = (unsigned short*)(ws + 89*MB);   // 18.9MB
  unsigned short* FRAW = (unsigned short*)(ws + 108*MB);  // 18.9MB
  unsigned short* GRAW = (unsigned short*)(ws + 127*MB);  // 18.9MB
  unsigned short* OBUF = (unsigned short*)(ws + 146*MB);  // 18.9MB
  float* HNEW = (float*)(ws + 165*MB);                    // 33.6MB
  unsigned short* SG = (unsigned short*)(ws + 89*MB);     // 67MB (reuses IRAW..OBUF, dead by then)
  float* CNEW = (float*)(ws + 199*MB);                    // 4.2MB
  float* OUT_H = (float*)d_out;
  float* OUT_C = (float*)d_out + 8388608;

  // ---- weight quantization (deterministic 2-stage) ----
  WList L;
  L.w[0]=wi;  L.n[0]=1048576ull; L.q[0]=WQ_WI;
  L.w[1]=wf;  L.n[1]=1048576ull; L.q[1]=WQ_WF;
  L.w[2]=wg;  L.n[2]=1048576ull; L.q[2]=WQ_WG;
  L.w[3]=wo;  L.n[3]=1048576ull; L.q[3]=WQ_WO;
  L.w[4]=ffg; L.n[4]=8388608ull; L.q[4]=WQ_FFG;
  L.w[5]=ffd; L.n[5]=4194304ull; L.q[5]=WQ_FFD;
  L.w[6]=fcg; L.n[6]=8388608ull; L.q[6]=WQ_FCG;
  L.w[7]=fcd; L.n[7]=4194304ull; L.q[7]=WQ_FCD;
  wq_reduce  <<<dim3(512,8), 256, 0, stream>>>(L, PART);
  wq_finalize<<<8,          256, 0, stream>>>(L, PART, SWINV);
  wq_quant   <<<dim3(1024,8),256, 0, stream>>>(L, SWINV);

  // ---- adaLN embeddings ----
  adaln_gemv<<<dim3(1536,2), 256, 0, stream>>>(temb, adaln_w,  adaln_b,  EH);
  adaln_gemv<<<dim3(1536,2), 256, 0, stream>>>(temb, adaln_cw, adaln_cb, EC);

  // ---- joint = [adaLN(enc); adaLN(hidden)], rmsnorm+quant ----
  modnorm_quant<<<1024, 256, 0, stream>>>(enc,    9,  EC, 0, 1024, XQ, RSX1, 0,   SJ);
  modnorm_quant<<<8192, 256, 0, stream>>>(hidden, 12, EH, 0, 1024, XQ, RSX1, 512, SJ);

  // ---- i, f, g bitlinears ----
  GemmP p{};
  p.rsx = RSX1;
  p.swinv = SWINV+0; p.outb = IRAW;
  gemm_bt<EPI_BF16><<<dim3(8,72), 256, 0, stream>>>(XQ, WQ_WI, 9216, 1024, 1024, p);
  p.swinv = SWINV+1; p.outb = FRAW;
  gemm_bt<EPI_BF16><<<dim3(8,72), 256, 0, stream>>>(XQ, WQ_WF, 9216, 1024, 1024, p);
  p.swinv = SWINV+2; p.outb = GRAW;
  gemm_bt<EPI_BF16><<<dim3(8,72), 256, 0, stream>>>(XQ, WQ_WG, 9216, 1024, 1024, p);

  // ---- HGRN scan (activations fused) ----
  scan_pass1<<<dim3(NCH,2), 256, 0, stream>>>(IRAW, FRAW, SCANA, SCANB);
  scan_pass2<<<8,           256, 0, stream>>>(SCANA, SCANB, SCANH);
  scan_pass3<<<dim3(NCH,2), 256, 0, stream>>>(IRAW, FRAW, SCANH, OBUF);

  // ---- gnorm + gate + quant ----
  gnorm_quant<<<9216, 256, 0, stream>>>(OBUF, GRAW, gnw, XQ, RSX2);

  // ---- wo bitlinear with gated residual split ----
  GemmP pw{};
  pw.rsx = RSX2; pw.swinv = SWINV+3;
  pw.eh = EH; pw.ec = EC; pw.hid = hidden; pw.enc = enc;
  pw.out_h = HNEW; pw.out_c = CNEW;
  gemm_bt<EPI_WO><<<dim3(8,72), 256, 0, stream>>>(XQ, WQ_WO, 9216, 1024, 1024, pw);

  // ---- image MLP ----
  modnorm_quant<<<8192, 256, 0, stream>>>(HNEW, 12, EH, 3*1024, 4*1024, XQ, RSX3, 0, SIMG);
  GemmP pg{};
  pg.rsx = RSX3; pg.swinv = SWINV+4; pg.outb = SG;
  gemm_bt<EPI_SILU><<<dim3(32,64), 256, 0, stream>>>(XQ, WQ_FFG,                      8192, 4096, 1024, pg);
  gemm_bt<EPI_MUL> <<<dim3(32,64), 256, 0, stream>>>(XQ, WQ_FFG + (size_t)4096*1024,  8192, 4096, 1024, pg);
  rmsq4096<<<8192, 256, 0, stream>>>(SG, RSXZ);
  GemmP pd{};
  pd.rsx = RSXZ; pd.swinv = SWINV+5; pd.outf = OUT_H; pd.resid = HNEW; pd.egate = EH; pd.bshift = 12;
  gemm_bt<EPI_RESID><<<dim3(8,64), 256, 0, stream>>>(SG, WQ_FFD, 8192, 1024, 4096, pd);

  // ---- context MLP ----
  modnorm_quant<<<1024, 256, 0, stream>>>(CNEW, 9, EC, 3*1024, 4*1024, XQ, RSX4, 0, SCTX);
  GemmP pc{};
  pc.rsx = RSX4; pc.swinv = SWINV+6; pc.outb = SG;
  gemm_bt<EPI_SILU><<<dim3(32,8), 256, 0, stream>>>(XQ, WQ_FCG,                      1024, 4096, 1024, pc);
  gemm_bt<EPI_MUL> <<<dim3(32,8), 256, 0, stream>>>(XQ, WQ_FCG + (size_t)4096*1024,  1024, 4096, 1024, pc);
  rmsq4096<<<1024, 256, 0, stream>>>(SG, RSXZC);
  GemmP pe{};
  pe.rsx = RSXZC; pe.swinv = SWINV+7; pe.outf = OUT_C; pe.resid = CNEW; pe.egate = EC; pe.bshift = 9;
  gemm_bt<EPI_RESID><<<dim3(8,8), 256, 0, stream>>>(SG, WQ_FCD, 1024, 1024, 4096, pe);
}

// Round 2
// 732.503 us; speedup vs baseline: 1.2869x; 1.2869x over previous
//
#include <hip/hip_runtime.h>
#include <hip/hip_bf16.h>
#include <stdint.h>

#define DM   1024
#define SJ   4608
#define SCTX 512
#define SIMG 4096
#define NCH  512
#define TCH  9

typedef __attribute__((ext_vector_type(8))) short bf16x8;
typedef __attribute__((ext_vector_type(4))) float f32x4;

__device__ __forceinline__ float bf2f(unsigned short u){
  union { unsigned int i; float f; } v; v.i = ((unsigned int)u) << 16; return v.f;
}
__device__ __forceinline__ unsigned short f2bf(float f){
  unsigned int u = __float_as_uint(f);
  u += 0x7fffu + ((u >> 16) & 1u);
  return (unsigned short)(u >> 16);
}
__device__ __forceinline__ float sigm(float x){ return 1.f/(1.f+__expf(-x)); }

__device__ __forceinline__ float wsum(float v){
  #pragma unroll
  for(int o=32;o>0;o>>=1) v += __shfl_xor(v,o);
  return v;
}
__device__ __forceinline__ float wmax(float v){
  #pragma unroll
  for(int o=32;o>0;o>>=1) v = fmaxf(v,__shfl_xor(v,o));
  return v;
}
__device__ __forceinline__ void blockSumSum(float& a, float& b, float* s1, float* s2){
  a = wsum(a); b = wsum(b);
  if(!(threadIdx.x&63)){ s1[threadIdx.x>>6]=a; s2[threadIdx.x>>6]=b; }
  __syncthreads();
  a = s1[0]+s1[1]+s1[2]+s1[3];
  b = s2[0]+s2[1]+s2[2]+s2[3];
  __syncthreads();
}
__device__ __forceinline__ void blockSumMax(float& a, float& b, float* s1, float* s2){
  a = wsum(a); b = wmax(b);
  if(!(threadIdx.x&63)){ s1[threadIdx.x>>6]=a; s2[threadIdx.x>>6]=b; }
  __syncthreads();
  a = s1[0]+s1[1]+s1[2]+s1[3];
  b = fmaxf(fmaxf(s2[0],s2[1]),fmaxf(s2[2],s2[3]));
  __syncthreads();
}

// ---------------- async global->LDS ----------------
typedef __attribute__((address_space(1))) void gvoid_t;
typedef __attribute__((address_space(3))) void lvoid_t;
__device__ __forceinline__ void gl_lds16(const void* g, void* l){
  __builtin_amdgcn_global_load_lds((gvoid_t*)g, (lvoid_t*)l, 16, 0, 0);
}

// ---------------- weight quantization ----------------
struct WList {
  const float* w[8];
  unsigned long long n[8];
  unsigned short* q[8];
};

__global__ __launch_bounds__(256)
void wq_reduce(WList L, float* __restrict__ part){
  __shared__ float s1[4];
  int m = blockIdx.y;
  const float4* w4 = (const float4*)L.w[m];
  size_t n4 = L.n[m] >> 2;
  float s = 0.f;
  for(size_t i = (size_t)blockIdx.x*256 + threadIdx.x; i < n4; i += (size_t)512*256){
    float4 v = w4[i];
    s += fabsf(v.x)+fabsf(v.y)+fabsf(v.z)+fabsf(v.w);
  }
  s = wsum(s);
  if(!(threadIdx.x&63)) s1[threadIdx.x>>6] = s;
  __syncthreads();
  if(!threadIdx.x) part[m*512 + blockIdx.x] = s1[0]+s1[1]+s1[2]+s1[3];
}

__global__ __launch_bounds__(256)
void wq_finalize(WList L, const float* __restrict__ part, float* __restrict__ swinv){
  __shared__ float s1[4];
  int m = blockIdx.x;
  float s = part[m*512 + threadIdx.x] + part[m*512 + 256 + threadIdx.x];
  s = wsum(s);
  if(!(threadIdx.x&63)) s1[threadIdx.x>>6] = s;
  __syncthreads();
  if(!threadIdx.x){
    float mean = (s1[0]+s1[1]+s1[2]+s1[3]) / (float)L.n[m];
    swinv[m] = fmaxf(mean, 1e-5f);
  }
}

__global__ __launch_bounds__(256)
void wq_quant(WList L, const float* __restrict__ swinv){
  int m = blockIdx.y;
  float sc = 1.f / swinv[m];
  const float4* w4 = (const float4*)L.w[m];
  unsigned short* q = L.q[m];
  size_t n4 = L.n[m] >> 2;
  for(size_t i = (size_t)blockIdx.x*256 + threadIdx.x; i < n4; i += (size_t)1024*256){
    float4 v = w4[i];
    ushort4 o;
    o.x = f2bf(fminf(fmaxf(rintf(v.x*sc),-1.f),1.f));
    o.y = f2bf(fminf(fmaxf(rintf(v.y*sc),-1.f),1.f));
    o.z = f2bf(fminf(fmaxf(rintf(v.z*sc),-1.f),1.f));
    o.w = f2bf(fminf(fmaxf(rintf(v.w*sc),-1.f),1.f));
    ((ushort4*)q)[i] = o;
  }
}

// ---------------- adaLN embedding GEMV ----------------
__global__ __launch_bounds__(256)
void adaln_gemv(const float* __restrict__ temb, const float* __restrict__ W,
                const float* __restrict__ bias, float* __restrict__ e){
  int o = blockIdx.x*4 + (threadIdx.x>>6);
  int b = blockIdx.y;
  int lane = threadIdx.x & 63;
  const float4* t4 = (const float4*)(temb + b*DM);
  const float4* w4 = (const float4*)(W + (size_t)o*DM);
  float acc = 0.f;
  #pragma unroll
  for(int i=0;i<4;i++){
    float4 tv = t4[i*64+lane], wv = w4[i*64+lane];
    acc += (tv.x*sigm(tv.x))*wv.x + (tv.y*sigm(tv.y))*wv.y
         + (tv.z*sigm(tv.z))*wv.z + (tv.w*sigm(tv.w))*wv.w;
  }
  acc = wsum(acc);
  if(!lane) e[b*6144 + o] = acc + bias[o];
}

// ---------------- LN -> adaLN modulate -> rmsnorm -> act_quant ----------------
__global__ __launch_bounds__(256)
void modnorm_quant(const float* __restrict__ x, int bshift,
                   const float* __restrict__ e, int scaleOff, int shiftOff,
                   unsigned short* __restrict__ xq, float* __restrict__ rsx,
                   int outRowOff, int outBatchStride){
  __shared__ float s1[4], s2[4];
  const int tid = threadIdx.x;
  const int row = blockIdx.x;
  const int b = row >> bshift, s = row & ((1<<bshift)-1);
  float4 xv = ((const float4*)(x + (size_t)row*DM))[tid];
  float sum = xv.x+xv.y+xv.z+xv.w;
  float ss  = xv.x*xv.x+xv.y*xv.y+xv.z*xv.z+xv.w*xv.w;
  blockSumSum(sum, ss, s1, s2);
  float mu  = sum * (1.f/DM);
  float inv = rsqrtf(ss*(1.f/DM) - mu*mu + 1e-6f);
  float4 scv = ((const float4*)(e + b*6144 + scaleOff))[tid];
  float4 shv = ((const float4*)(e + b*6144 + shiftOff))[tid];
  float n0 = (xv.x-mu)*inv*(1.f+scv.x)+shv.x;
  float n1 = (xv.y-mu)*inv*(1.f+scv.y)+shv.y;
  float n2 = (xv.z-mu)*inv*(1.f+scv.z)+shv.z;
  float n3 = (xv.w-mu)*inv*(1.f+scv.w)+shv.w;
  float ss2 = n0*n0+n1*n1+n2*n2+n3*n3;
  float mx  = fmaxf(fmaxf(fabsf(n0),fabsf(n1)),fmaxf(fabsf(n2),fabsf(n3)));
  blockSumMax(ss2, mx, s1, s2);
  float rms   = rsqrtf(ss2*(1.f/DM) + 1e-6f);
  float amaxn = fmaxf(mx*rms, 1e-5f);
  float k     = rms*127.f/amaxn;
  int orow = b*outBatchStride + outRowOff + s;
  ushort4 q;
  q.x = f2bf(fminf(fmaxf(rintf(n0*k),-128.f),127.f));
  q.y = f2bf(fminf(fmaxf(rintf(n1*k),-128.f),127.f));
  q.z = f2bf(fminf(fmaxf(rintf(n2*k),-128.f),127.f));
  q.w = f2bf(fminf(fmaxf(rintf(n3*k),-128.f),127.f));
  ((ushort4*)(xq + (size_t)orow*DM))[tid] = q;
  if(!tid) rsx[orow] = amaxn*(1.f/127.f);
}

// ---------------- rmsnorm(o)*gnw*silu(g) -> rmsnorm -> act_quant ----------------
__global__ __launch_bounds__(256)
void gnorm_quant(const unsigned short* __restrict__ o, const unsigned short* __restrict__ g,
                 const float* __restrict__ gnw,
                 unsigned short* __restrict__ xq, float* __restrict__ rsx){
  __shared__ float s1[4], s2[4];
  const int tid = threadIdx.x;
  const size_t row = blockIdx.x;
  ushort4 ov = ((const ushort4*)(o + row*DM))[tid];
  ushort4 gv = ((const ushort4*)(g + row*DM))[tid];
  float o0=bf2f(ov.x), o1=bf2f(ov.y), o2=bf2f(ov.z), o3=bf2f(ov.w);
  float g0=bf2f(gv.x), g1=bf2f(gv.y), g2=bf2f(gv.z), g3=bf2f(gv.w);
  float ss = o0*o0+o1*o1+o2*o2+o3*o3;
  float dummy = 0.f;
  blockSumSum(ss, dummy, s1, s2);
  float rms = rsqrtf(ss*(1.f/DM) + 1e-6f);
  float4 wv = ((const float4*)gnw)[tid];
  float n0 = o0*rms*wv.x*(g0*sigm(g0));
  float n1 = o1*rms*wv.y*(g1*sigm(g1));
  float n2 = o2*rms*wv.z*(g2*sigm(g2));
  float n3 = o3*rms*wv.w*(g3*sigm(g3));
  float ss2 = n0*n0+n1*n1+n2*n2+n3*n3;
  float mx  = fmaxf(fmaxf(fabsf(n0),fabsf(n1)),fmaxf(fabsf(n2),fabsf(n3)));
  blockSumMax(ss2, mx, s1, s2);
  float rms2  = rsqrtf(ss2*(1.f/DM) + 1e-6f);
  float amaxn = fmaxf(mx*rms2, 1e-5f);
  float k     = rms2*127.f/amaxn;
  ushort4 q;
  q.x = f2bf(fminf(fmaxf(rintf(n0*k),-128.f),127.f));
  q.y = f2bf(fminf(fmaxf(rintf(n1*k),-128.f),127.f));
  q.z = f2bf(fminf(fmaxf(rintf(n2*k),-128.f),127.f));
  q.w = f2bf(fminf(fmaxf(rintf(n3*k),-128.f),127.f));
  ((ushort4*)(xq + row*DM))[tid] = q;
  if(!tid) rsx[row] = amaxn*(1.f/127.f);
}

// ---------------- rmsnorm -> act_quant, in-place, D=4096 bf16 rows ----------------
__global__ __launch_bounds__(256)
void rmsq4096(unsigned short* __restrict__ z, float* __restrict__ rsx){
  __shared__ float s1[4], s2[4];
  const int tid = threadIdx.x;
  unsigned short* zr = z + (size_t)blockIdx.x*4096;
  float v[16];
  #pragma unroll
  for(int i=0;i<4;i++){
    ushort4 u = ((const ushort4*)zr)[tid + i*256];
    v[i*4+0]=bf2f(u.x); v[i*4+1]=bf2f(u.y); v[i*4+2]=bf2f(u.z); v[i*4+3]=bf2f(u.w);
  }
  float ss=0.f, mx=0.f;
  #pragma unroll
  for(int i=0;i<16;i++){ ss += v[i]*v[i]; mx = fmaxf(mx, fabsf(v[i])); }
  blockSumMax(ss, mx, s1, s2);
  float rms   = rsqrtf(ss*(1.f/4096.f) + 1e-6f);
  float amaxn = fmaxf(mx*rms, 1e-5f);
  float k     = rms*127.f/amaxn;
  #pragma unroll
  for(int i=0;i<4;i++){
    ushort4 q;
    q.x = f2bf(fminf(fmaxf(rintf(v[i*4+0]*k),-128.f),127.f));
    q.y = f2bf(fminf(fmaxf(rintf(v[i*4+1]*k),-128.f),127.f));
    q.z = f2bf(fminf(fmaxf(rintf(v[i*4+2]*k),-128.f),127.f));
    q.w = f2bf(fminf(fmaxf(rintf(v[i*4+3]*k),-128.f),127.f));
    ((ushort4*)zr)[tid + i*256] = q;
  }
  if(!tid) rsx[blockIdx.x] = amaxn*(1.f/127.f);
}

// ---------------- HGRN chunked scan ----------------
__global__ __launch_bounds__(256)
void scan_pass1(const unsigned short* __restrict__ ir, const unsigned short* __restrict__ fr,
                float* __restrict__ A, float* __restrict__ B){
  int c = blockIdx.x, b = blockIdx.y;
  int d0 = threadIdx.x*4;
  size_t base = ((size_t)b*SJ + (size_t)c*TCH)*DM + d0;
  float a0=1,a1=1,a2=1,a3=1, h0=0,h1=0,h2=0,h3=0;
  #pragma unroll
  for(int t=0;t<TCH;t++){
    ushort4 iv = *(const ushort4*)(ir + base + (size_t)t*DM);
    ushort4 fv = *(const ushort4*)(fr + base + (size_t)t*DM);
    float f0=sigm(bf2f(fv.x)), f1=sigm(bf2f(fv.y)), f2=sigm(bf2f(fv.z)), f3=sigm(bf2f(fv.w));
    float x0=bf2f(iv.x), x1=bf2f(iv.y), x2=bf2f(iv.z), x3=bf2f(iv.w);
    float p0=x0*sigm(x0)*(1.f-f0), p1=x1*sigm(x1)*(1.f-f1);
    float p2=x2*sigm(x2)*(1.f-f2), p3=x3*sigm(x3)*(1.f-f3);
    h0=f0*h0+p0; h1=f1*h1+p1; h2=f2*h2+p2; h3=f3*h3+p3;
    a0*=f0; a1*=f1; a2*=f2; a3*=f3;
  }
  size_t idx = (size_t)c*2048 + b*1024 + d0;
  *(float4*)(A + idx) = make_float4(a0,a1,a2,a3);
  *(float4*)(B + idx) = make_float4(h0,h1,h2,h3);
}

__global__ __launch_bounds__(256)
void scan_pass2(const float* __restrict__ A, const float* __restrict__ B, float* __restrict__ H){
  int chain = blockIdx.x*256 + threadIdx.x;
  float h = 0.f;
  for(int c0=0;c0<NCH;c0+=8){
    float a[8], bb[8];
    #pragma unroll
    for(int u=0;u<8;u++){
      a[u]  = A[(size_t)(c0+u)*2048 + chain];
      bb[u] = B[(size_t)(c0+u)*2048 + chain];
    }
    #pragma unroll
    for(int u=0;u<8;u++){
      H[(size_t)(c0+u)*2048 + chain] = h;
      h = a[u]*h + bb[u];
    }
  }
}

__global__ __launch_bounds__(256)
void scan_pass3(const unsigned short* __restrict__ ir, const unsigned short* __restrict__ fr,
                const float* __restrict__ H, unsigned short* __restrict__ o){
  int c = blockIdx.x, b = blockIdx.y;
  int d0 = threadIdx.x*4;
  size_t base = ((size_t)b*SJ + (size_t)c*TCH)*DM + d0;
  float4 hv = *(const float4*)(H + (size_t)c*2048 + b*1024 + d0);
  float h0=hv.x, h1=hv.y, h2=hv.z, h3=hv.w;
  #pragma unroll
  for(int t=0;t<TCH;t++){
    ushort4 iv = *(const ushort4*)(ir + base + (size_t)t*DM);
    ushort4 fv = *(const ushort4*)(fr + base + (size_t)t*DM);
    float f0=sigm(bf2f(fv.x)), f1=sigm(bf2f(fv.y)), f2=sigm(bf2f(fv.z)), f3=sigm(bf2f(fv.w));
    float x0=bf2f(iv.x), x1=bf2f(iv.y), x2=bf2f(iv.z), x3=bf2f(iv.w);
    float p0=x0*sigm(x0)*(1.f-f0), p1=x1*sigm(x1)*(1.f-f1);
    float p2=x2*sigm(x2)*(1.f-f2), p3=x3*sigm(x3)*(1.f-f3);
    h0=f0*h0+p0; h1=f1*h1+p1; h2=f2*h2+p2; h3=f3*h3+p3;
    ushort4 ov; ov.x=f2bf(h0); ov.y=f2bf(h1); ov.z=f2bf(h2); ov.w=f2bf(h3);
    *(ushort4*)(o + base + (size_t)t*DM) = ov;
  }
}

// ---------------- bf16 MFMA GEMM, BK=64, 128x128 tile, templated epilogue ----------------
#define EPI_IFG    0
#define EPI_WO     1
#define EPI_GLU    2
#define EPI_RESID  3
#define EPI_RESIDA 4

struct GemmP {
  const float* rsx;
  const float* swinv;
  unsigned short* outb;
  float* outf;
  const float* resid;
  const float* egate;
  int bshift;
  const unsigned short* w2;              // GLU second-half weights
  const float* eh; const float* ec;      // WO gates (chunk 2)
  const float* hid; const float* enc;    // WO residual bases
  float* out_h; float* out_c; float* out_c2;
};

template<int EPI>
__global__ __launch_bounds__(256, 2)
void gemm_bt(const unsigned short* __restrict__ Aq, const unsigned short* __restrict__ Wq,
             int M, int N, int K, int lda, GemmP p){
  __shared__ unsigned short As[128*64];
  __shared__ unsigned short Bs[(EPI==EPI_GLU?2:1)*128*64];
  const int tid = threadIdx.x;
  const int wave = tid>>6, lane = tid&63;

  // XCD-aware bijective swizzle: all launches have nwg % 8 == 0
  const int nwg = gridDim.x*gridDim.y;
  const int id  = blockIdx.y*gridDim.x + blockIdx.x;
  const int wg  = (id&7)*(nwg>>3) + (id>>3);
  const int nb  = wg % gridDim.x, mb = wg / gridDim.x;
  const int wr = wave>>1, wc = wave&1;
  const int koff = (EPI==EPI_RESIDA) ? blockIdx.z*K : 0;

  // staging: each wave stages 8 rows/pass, 4 passes per 128x64 tile
  const int grow = wave*8 + (lane>>3);
  const int gcol = (lane&7)*8;
  const unsigned short* ag = Aq + (size_t)(mb*128 + grow)*lda + koff + gcol;
  const unsigned short* bg = Wq + (size_t)(nb*128 + grow)*lda + koff + gcol;
  const unsigned short* b2g = nullptr;
  if constexpr (EPI==EPI_GLU) b2g = p.w2 + (size_t)(nb*128 + grow)*lda + gcol;
  char* asl = (char*)As + wave*1024;
  char* bsl = (char*)Bs + wave*1024;
  char* b2l = (char*)Bs + 16384 + wave*1024;

  f32x4 acc[4][4];
  f32x4 acc2[(EPI==EPI_GLU)?4:1][4];
  #pragma unroll
  for(int i=0;i<4;i++)
    #pragma unroll
    for(int j=0;j<4;j++) acc[i][j] = (f32x4){0.f,0.f,0.f,0.f};
  if constexpr (EPI==EPI_GLU){
    #pragma unroll
    for(int i=0;i<4;i++)
      #pragma unroll
      for(int j=0;j<4;j++) acc2[i][j] = (f32x4){0.f,0.f,0.f,0.f};
  }

  const int lrow = lane&15, lk8 = (lane>>4)*8;
  const unsigned short* arow = &As[(wr*64 + lrow)*64 + lk8];
  const unsigned short* brow = &Bs[(wc*64 + lrow)*64 + lk8];

  for(int k0=0; k0<K; k0+=64){
    #pragma unroll
    for(int pp=0;pp<4;pp++){
      gl_lds16(ag + (size_t)pp*32*lda + k0, asl + pp*4096);
      gl_lds16(bg + (size_t)pp*32*lda + k0, bsl + pp*4096);
      if constexpr (EPI==EPI_GLU)
        gl_lds16(b2g + (size_t)pp*32*lda + k0, b2l + pp*4096);
    }
    __syncthreads();
    #pragma unroll
    for(int kk=0;kk<2;kk++){
      bf16x8 af[4], bfr[4];
      #pragma unroll
      for(int m=0;m<4;m++) af[m]  = *(const bf16x8*)(arow + m*1024 + kk*32);
      #pragma unroll
      for(int n=0;n<4;n++) bfr[n] = *(const bf16x8*)(brow + n*1024 + kk*32);
      #pragma unroll
      for(int m=0;m<4;m++)
        #pragma unroll
        for(int n=0;n<4;n++)
          acc[m][n] = __builtin_amdgcn_mfma_f32_16x16x32_bf16(af[m], bfr[n], acc[m][n], 0,0,0);
      if constexpr (EPI==EPI_GLU){
        #pragma unroll
        for(int n=0;n<4;n++) bfr[n] = *(const bf16x8*)(brow + 8192 + n*1024 + kk*32);
        #pragma unroll
        for(int m=0;m<4;m++)
          #pragma unroll
          for(int n=0;n<4;n++)
            acc2[m][n] = __builtin_amdgcn_mfma_f32_16x16x32_bf16(af[m], bfr[n], acc2[m][n], 0,0,0);
      }
    }
    __syncthreads();
  }

  float sw;
  if constexpr (EPI==EPI_IFG) sw = p.swinv[(nb*128)>>10];
  else                        sw = *p.swinv;
  const int r0 = mb*128 + wr*64, c0 = nb*128 + wc*64;
  #pragma unroll
  for(int m=0;m<4;m++){
    #pragma unroll
    for(int j=0;j<4;j++){
      int r = r0 + m*16 + ((lane>>4)<<2) + j;
      float rs = p.rsx[r]*sw;
      #pragma unroll
      for(int n=0;n<4;n++){
        int c = c0 + n*16 + (lane&15);
        float val = acc[m][n][j]*rs;
        if constexpr (EPI==EPI_IFG){
          int mat = c >> 10;
          p.outb[(size_t)mat*9437184 + (size_t)r*1024 + (c&1023)] = f2bf(val);
        } else if constexpr (EPI==EPI_GLU){
          float v2 = acc2[m][n][j]*rs;
          p.outb[(size_t)r*N + c] = f2bf(val*sigm(val)*v2);
        } else if constexpr (EPI==EPI_RESID){
          int b = r >> p.bshift;
          size_t idx = (size_t)r*DM + c;
          p.outf[idx] = p.resid[idx] + p.egate[b*6144 + 5*1024 + c]*val;
        } else if constexpr (EPI==EPI_RESIDA){
          int b = r >> p.bshift;
          size_t idx = (size_t)r*DM + c;
          atomicAdd(&p.outf[idx], p.egate[b*6144 + 5*1024 + c]*val);
        } else { // EPI_WO
          int b = r / SJ; int s = r - b*SJ;
          if (s < SCTX){
            size_t idx = ((size_t)b*SCTX + s)*DM + c;
            float ov = p.enc[idx] + p.ec[b*6144 + 2*1024 + c]*val;
            p.out_c[idx]  = ov;
            p.out_c2[idx] = ov;
          } else {
            size_t idx = ((size_t)b*SIMG + (s-SCTX))*DM + c;
            p.out_h[idx] = p.hid[idx] + p.eh[b*6144 + 2*1024 + c]*val;
          }
        }
      }
    }
  }
}

// ================= host =================
extern "C" void kernel_launch(void* const* d_in, const int* in_sizes, int n_in,
                              void* d_out, int out_size, void* d_ws, size_t ws_size,
                              hipStream_t stream){
  (void)in_sizes; (void)n_in; (void)out_size; (void)ws_size;
  const float* hidden   = (const float*)d_in[0];
  const float* enc      = (const float*)d_in[1];
  const float* temb     = (const float*)d_in[2];
  const float* adaln_w  = (const float*)d_in[3];
  const float* adaln_b  = (const float*)d_in[4];
  const float* adaln_cw = (const float*)d_in[5];
  const float* adaln_cb = (const float*)d_in[6];
  const float* wi  = (const float*)d_in[7];
  const float* wf  = (const float*)d_in[8];
  const float* wg  = (const float*)d_in[9];
  const float* wo  = (const float*)d_in[10];
  const float* gnw = (const float*)d_in[11];
  const float* ffg = (const float*)d_in[12];
  const float* ffd = (const float*)d_in[13];
  const float* fcg = (const float*)d_in[14];
  const float* fcd = (const float*)d_in[15];

  const size_t MB = 1024ull*1024ull;
  char* ws = (char*)d_ws;
  unsigned short* WQ_WI  = (unsigned short*)(ws + 0*MB);   // I/F/G contiguous: 3072x1024
  unsigned short* WQ_WF  = (unsigned short*)(ws + 2*MB);
  unsigned short* WQ_WG  = (unsigned short*)(ws + 4*MB);
  unsigned short* WQ_WO  = (unsigned short*)(ws + 6*MB);
  unsigned short* WQ_FFG = (unsigned short*)(ws + 8*MB);
  unsigned short* WQ_FFD = (unsigned short*)(ws + 24*MB);
  unsigned short* WQ_FCG = (unsigned short*)(ws + 32*MB);
  unsigned short* WQ_FCD = (unsigned short*)(ws + 48*MB);
  float* PART  = (float*)(ws + 56*MB);
  float* SWINV = (float*)(ws + 56*MB + 32*1024);
  float* EH    = (float*)(ws + 56*MB + 64*1024);
  float* EC    = (float*)(ws + 56*MB + 112*1024);
  float* RSX1  = (float*)(ws + 56*MB + 160*1024);
  float* RSX2  = (float*)(ws + 56*MB + 200*1024);
  float* RSX3  = (float*)(ws + 56*MB + 240*1024);
  float* RSXZ  = (float*)(ws + 56*MB + 280*1024);
  float* RSX4  = (float*)(ws + 56*MB + 320*1024);
  float* RSXZC = (float*)(ws + 56*MB + 328*1024);
  float* SCANA = (float*)(ws + 57*MB);
  float* SCANB = (float*)(ws + 61*MB);
  float* SCANH = (float*)(ws + 65*MB);
  unsigned short* XQ   = (unsigned short*)(ws + 70*MB);    // 18 MB
  unsigned short* IRAW = (unsigned short*)(ws + 89*MB);    // 18 MB, stride 9437184 elems
  unsigned short* FRAW = (unsigned short*)(ws + 107*MB);
  unsigned short* GRAW = (unsigned short*)(ws + 125*MB);
  unsigned short* OBUF = (unsigned short*)(ws + 143*MB);
  float* HNEW = (float*)(ws + 165*MB);                     // 33.6 MB
  unsigned short* SG = (unsigned short*)(ws + 89*MB);      // 67 MB, reuses IRAW..OBUF
  float* CNEW = (float*)(ws + 199*MB);
  float* OUT_H = (float*)d_out;
  float* OUT_C = (float*)d_out + 8388608;

  // ---- weight quantization ----
  WList L;
  L.w[0]=wi;  L.n[0]=1048576ull; L.q[0]=WQ_WI;
  L.w[1]=wf;  L.n[1]=1048576ull; L.q[1]=WQ_WF;
  L.w[2]=wg;  L.n[2]=1048576ull; L.q[2]=WQ_WG;
  L.w[3]=wo;  L.n[3]=1048576ull; L.q[3]=WQ_WO;
  L.w[4]=ffg; L.n[4]=8388608ull; L.q[4]=WQ_FFG;
  L.w[5]=ffd; L.n[5]=4194304ull; L.q[5]=WQ_FFD;
  L.w[6]=fcg; L.n[6]=8388608ull; L.q[6]=WQ_FCG;
  L.w[7]=fcd; L.n[7]=4194304ull; L.q[7]=WQ_FCD;
  wq_reduce  <<<dim3(512,8), 256, 0, stream>>>(L, PART);
  wq_finalize<<<8,          256, 0, stream>>>(L, PART, SWINV);
  wq_quant   <<<dim3(1024,8),256, 0, stream>>>(L, SWINV);

  // ---- adaLN embeddings ----
  adaln_gemv<<<dim3(1536,2), 256, 0, stream>>>(temb, adaln_w,  adaln_b,  EH);
  adaln_gemv<<<dim3(1536,2), 256, 0, stream>>>(temb, adaln_cw, adaln_cb, EC);

  // ---- joint = [adaLN(enc); adaLN(hidden)], rmsnorm+quant ----
  modnorm_quant<<<1024, 256, 0, stream>>>(enc,    9,  EC, 0, 1024, XQ, RSX1, 0,   SJ);
  modnorm_quant<<<8192, 256, 0, stream>>>(hidden, 12, EH, 0, 1024, XQ, RSX1, 512, SJ);

  // ---- merged i/f/g bitlinear (N=3072) ----
  GemmP p{};
  p.rsx = RSX1; p.swinv = SWINV; p.outb = IRAW;
  gemm_bt<EPI_IFG><<<dim3(24,72), 256, 0, stream>>>(XQ, WQ_WI, 9216, 3072, 1024, 1024, p);

  // ---- HGRN scan ----
  scan_pass1<<<dim3(NCH,2), 256, 0, stream>>>(IRAW, FRAW, SCANA, SCANB);
  scan_pass2<<<8,           256, 0, stream>>>(SCANA, SCANB, SCANH);
  scan_pass3<<<dim3(NCH,2), 256, 0, stream>>>(IRAW, FRAW, SCANH, OBUF);

  // ---- gnorm + gate + quant ----
  gnorm_quant<<<9216, 256, 0, stream>>>(OBUF, GRAW, gnw, XQ, RSX2);

  // ---- wo bitlinear with gated residual split (also pre-fills OUT_C) ----
  GemmP pw{};
  pw.rsx = RSX2; pw.swinv = SWINV+3;
  pw.eh = EH; pw.ec = EC; pw.hid = hidden; pw.enc = enc;
  pw.out_h = HNEW; pw.out_c = CNEW; pw.out_c2 = OUT_C;
  gemm_bt<EPI_WO><<<dim3(8,72), 256, 0, stream>>>(XQ, WQ_WO, 9216, 1024, 1024, 1024, pw);

  // ---- image MLP ----
  modnorm_quant<<<8192, 256, 0, stream>>>(HNEW, 12, EH, 3*1024, 4*1024, XQ, RSX3, 0, SIMG);
  GemmP pg{};
  pg.rsx = RSX3; pg.swinv = SWINV+4; pg.outb = SG; pg.w2 = WQ_FFG + (size_t)4096*1024;
  gemm_bt<EPI_GLU><<<dim3(32,64), 256, 0, stream>>>(XQ, WQ_FFG, 8192, 4096, 1024, 1024, pg);
  rmsq4096<<<8192, 256, 0, stream>>>(SG, RSXZ);
  GemmP pd{};
  pd.rsx = RSXZ; pd.swinv = SWINV+5; pd.outf = OUT_H; pd.resid = HNEW; pd.egate = EH; pd.bshift = 12;
  gemm_bt<EPI_RESID><<<dim3(8,64), 256, 0, stream>>>(SG, WQ_FFD, 8192, 1024, 4096, 4096, pd);

  // ---- context MLP ----
  modnorm_quant<<<1024, 256, 0, stream>>>(CNEW, 9, EC, 3*1024, 4*1024, XQ, RSX4, 0, SCTX);
  GemmP pc{};
  pc.rsx = RSX4; pc.swinv = SWINV+6; pc.outb = SG; pc.w2 = WQ_FCG + (size_t)4096*1024;
  gemm_bt<EPI_GLU><<<dim3(32,8), 256, 0, stream>>>(XQ, WQ_FCG, 1024, 4096, 1024, 1024, pc);
  rmsq4096<<<1024, 256, 0, stream>>>(SG, RSXZC);
  GemmP pe{};
  pe.rsx = RSXZC; pe.swinv = SWINV+7; pe.outf = OUT_C; pe.egate = EC; pe.bshift = 9;
  gemm_bt<EPI_RESIDA><<<dim3(8,8,4), 256, 0, stream>>>(SG, WQ_FCD, 1024, 1024, 1024, 4096, pe);
}

// Round 3
// 665.433 us; speedup vs baseline: 1.4166x; 1.1008x over previous
//
#include <hip/hip_runtime.h>
#include <hip/hip_bf16.h>
#include <stdint.h>

#define DM   1024
#define SJ   4608
#define SCTX 512
#define SIMG 4096
#define NCH  512
#define TCH  9

typedef __attribute__((ext_vector_type(8))) short bf16x8;
typedef __attribute__((ext_vector_type(4))) float f32x4;

__device__ __forceinline__ float bf2f(unsigned short u){
  union { unsigned int i; float f; } v; v.i = ((unsigned int)u) << 16; return v.f;
}
__device__ __forceinline__ unsigned short f2bf(float f){
  unsigned int u = __float_as_uint(f);
  u += 0x7fffu + ((u >> 16) & 1u);
  return (unsigned short)(u >> 16);
}
__device__ __forceinline__ float sigm(float x){ return 1.f/(1.f+__expf(-x)); }

__device__ __forceinline__ float wsum(float v){
  #pragma unroll
  for(int o=32;o>0;o>>=1) v += __shfl_xor(v,o);
  return v;
}
__device__ __forceinline__ float wmax(float v){
  #pragma unroll
  for(int o=32;o>0;o>>=1) v = fmaxf(v,__shfl_xor(v,o));
  return v;
}
__device__ __forceinline__ void blockSumSum(float& a, float& b, float* s1, float* s2){
  a = wsum(a); b = wsum(b);
  if(!(threadIdx.x&63)){ s1[threadIdx.x>>6]=a; s2[threadIdx.x>>6]=b; }
  __syncthreads();
  a = s1[0]+s1[1]+s1[2]+s1[3];
  b = s2[0]+s2[1]+s2[2]+s2[3];
  __syncthreads();
}
__device__ __forceinline__ void blockSumMax(float& a, float& b, float* s1, float* s2){
  a = wsum(a); b = wmax(b);
  if(!(threadIdx.x&63)){ s1[threadIdx.x>>6]=a; s2[threadIdx.x>>6]=b; }
  __syncthreads();
  a = s1[0]+s1[1]+s1[2]+s1[3];
  b = fmaxf(fmaxf(s2[0],s2[1]),fmaxf(s2[2],s2[3]));
  __syncthreads();
}

// ---------------- async global->LDS ----------------
typedef __attribute__((address_space(1))) void gvoid_t;
typedef __attribute__((address_space(3))) void lvoid_t;
__device__ __forceinline__ void gl_lds16(const void* g, void* l){
  __builtin_amdgcn_global_load_lds((gvoid_t*)g, (lvoid_t*)l, 16, 0, 0);
}

// ---------------- weight quantization ----------------
struct WList {
  const float* w[8];
  unsigned long long n[8];
  unsigned short* q[8];
};

__global__ __launch_bounds__(256)
void wq_reduce(WList L, float* __restrict__ part){
  __shared__ float s1[4];
  int m = blockIdx.y;
  const float4* w4 = (const float4*)L.w[m];
  size_t n4 = L.n[m] >> 2;
  float s = 0.f;
  for(size_t i = (size_t)blockIdx.x*256 + threadIdx.x; i < n4; i += (size_t)512*256){
    float4 v = w4[i];
    s += fabsf(v.x)+fabsf(v.y)+fabsf(v.z)+fabsf(v.w);
  }
  s = wsum(s);
  if(!(threadIdx.x&63)) s1[threadIdx.x>>6] = s;
  __syncthreads();
  if(!threadIdx.x) part[m*512 + blockIdx.x] = s1[0]+s1[1]+s1[2]+s1[3];
}

__global__ __launch_bounds__(256)
void wq_finalize(WList L, const float* __restrict__ part, float* __restrict__ swinv){
  __shared__ float s1[4];
  int m = blockIdx.x;
  float s = part[m*512 + threadIdx.x] + part[m*512 + 256 + threadIdx.x];
  s = wsum(s);
  if(!(threadIdx.x&63)) s1[threadIdx.x>>6] = s;
  __syncthreads();
  if(!threadIdx.x){
    float mean = (s1[0]+s1[1]+s1[2]+s1[3]) / (float)L.n[m];
    swinv[m] = fmaxf(mean, 1e-5f);
  }
}

__global__ __launch_bounds__(256)
void wq_quant(WList L, const float* __restrict__ swinv){
  int m = blockIdx.y;
  float sc = 1.f / swinv[m];
  const float4* w4 = (const float4*)L.w[m];
  unsigned short* q = L.q[m];
  size_t n4 = L.n[m] >> 2;
  for(size_t i = (size_t)blockIdx.x*256 + threadIdx.x; i < n4; i += (size_t)1024*256){
    float4 v = w4[i];
    ushort4 o;
    o.x = f2bf(fminf(fmaxf(rintf(v.x*sc),-1.f),1.f));
    o.y = f2bf(fminf(fmaxf(rintf(v.y*sc),-1.f),1.f));
    o.z = f2bf(fminf(fmaxf(rintf(v.z*sc),-1.f),1.f));
    o.w = f2bf(fminf(fmaxf(rintf(v.w*sc),-1.f),1.f));
    ((ushort4*)q)[i] = o;
  }
}

// ---------------- adaLN embedding GEMV ----------------
__global__ __launch_bounds__(256)
void adaln_gemv(const float* __restrict__ temb, const float* __restrict__ W,
                const float* __restrict__ bias, float* __restrict__ e){
  int o = blockIdx.x*4 + (threadIdx.x>>6);
  int b = blockIdx.y;
  int lane = threadIdx.x & 63;
  const float4* t4 = (const float4*)(temb + b*DM);
  const float4* w4 = (const float4*)(W + (size_t)o*DM);
  float acc = 0.f;
  #pragma unroll
  for(int i=0;i<4;i++){
    float4 tv = t4[i*64+lane], wv = w4[i*64+lane];
    acc += (tv.x*sigm(tv.x))*wv.x + (tv.y*sigm(tv.y))*wv.y
         + (tv.z*sigm(tv.z))*wv.z + (tv.w*sigm(tv.w))*wv.w;
  }
  acc = wsum(acc);
  if(!lane) e[b*6144 + o] = acc + bias[o];
}

// ---------------- LN -> adaLN modulate -> rmsnorm -> act_quant ----------------
__global__ __launch_bounds__(256)
void modnorm_quant(const float* __restrict__ x, int bshift,
                   const float* __restrict__ e, int scaleOff, int shiftOff,
                   unsigned short* __restrict__ xq, float* __restrict__ rsx,
                   int outRowOff, int outBatchStride){
  __shared__ float s1[4], s2[4];
  const int tid = threadIdx.x;
  const int row = blockIdx.x;
  const int b = row >> bshift, s = row & ((1<<bshift)-1);
  float4 xv = ((const float4*)(x + (size_t)row*DM))[tid];
  float sum = xv.x+xv.y+xv.z+xv.w;
  float ss  = xv.x*xv.x+xv.y*xv.y+xv.z*xv.z+xv.w*xv.w;
  blockSumSum(sum, ss, s1, s2);
  float mu  = sum * (1.f/DM);
  float inv = rsqrtf(ss*(1.f/DM) - mu*mu + 1e-6f);
  float4 scv = ((const float4*)(e + b*6144 + scaleOff))[tid];
  float4 shv = ((const float4*)(e + b*6144 + shiftOff))[tid];
  float n0 = (xv.x-mu)*inv*(1.f+scv.x)+shv.x;
  float n1 = (xv.y-mu)*inv*(1.f+scv.y)+shv.y;
  float n2 = (xv.z-mu)*inv*(1.f+scv.z)+shv.z;
  float n3 = (xv.w-mu)*inv*(1.f+scv.w)+shv.w;
  float ss2 = n0*n0+n1*n1+n2*n2+n3*n3;
  float mx  = fmaxf(fmaxf(fabsf(n0),fabsf(n1)),fmaxf(fabsf(n2),fabsf(n3)));
  blockSumMax(ss2, mx, s1, s2);
  float rms   = rsqrtf(ss2*(1.f/DM) + 1e-6f);
  float amaxn = fmaxf(mx*rms, 1e-5f);
  float k     = rms*127.f/amaxn;
  int orow = b*outBatchStride + outRowOff + s;
  ushort4 q;
  q.x = f2bf(fminf(fmaxf(rintf(n0*k),-128.f),127.f));
  q.y = f2bf(fminf(fmaxf(rintf(n1*k),-128.f),127.f));
  q.z = f2bf(fminf(fmaxf(rintf(n2*k),-128.f),127.f));
  q.w = f2bf(fminf(fmaxf(rintf(n3*k),-128.f),127.f));
  ((ushort4*)(xq + (size_t)orow*DM))[tid] = q;
  if(!tid) rsx[orow] = amaxn*(1.f/127.f);
}

// ---------------- rmsnorm(o)*gnw*silu(g) -> rmsnorm -> act_quant ----------------
__global__ __launch_bounds__(256)
void gnorm_quant(const unsigned short* __restrict__ o, const unsigned short* __restrict__ g,
                 const float* __restrict__ gnw,
                 unsigned short* __restrict__ xq, float* __restrict__ rsx){
  __shared__ float s1[4], s2[4];
  const int tid = threadIdx.x;
  const size_t row = blockIdx.x;
  ushort4 ov = ((const ushort4*)(o + row*DM))[tid];
  ushort4 gv = ((const ushort4*)(g + row*DM))[tid];
  float o0=bf2f(ov.x), o1=bf2f(ov.y), o2=bf2f(ov.z), o3=bf2f(ov.w);
  float g0=bf2f(gv.x), g1=bf2f(gv.y), g2=bf2f(gv.z), g3=bf2f(gv.w);
  float ss = o0*o0+o1*o1+o2*o2+o3*o3;
  float dummy = 0.f;
  blockSumSum(ss, dummy, s1, s2);
  float rms = rsqrtf(ss*(1.f/DM) + 1e-6f);
  float4 wv = ((const float4*)gnw)[tid];
  float n0 = o0*rms*wv.x*(g0*sigm(g0));
  float n1 = o1*rms*wv.y*(g1*sigm(g1));
  float n2 = o2*rms*wv.z*(g2*sigm(g2));
  float n3 = o3*rms*wv.w*(g3*sigm(g3));
  float ss2 = n0*n0+n1*n1+n2*n2+n3*n3;
  float mx  = fmaxf(fmaxf(fabsf(n0),fabsf(n1)),fmaxf(fabsf(n2),fabsf(n3)));
  blockSumMax(ss2, mx, s1, s2);
  float rms2  = rsqrtf(ss2*(1.f/DM) + 1e-6f);
  float amaxn = fmaxf(mx*rms2, 1e-5f);
  float k     = rms2*127.f/amaxn;
  ushort4 q;
  q.x = f2bf(fminf(fmaxf(rintf(n0*k),-128.f),127.f));
  q.y = f2bf(fminf(fmaxf(rintf(n1*k),-128.f),127.f));
  q.z = f2bf(fminf(fmaxf(rintf(n2*k),-128.f),127.f));
  q.w = f2bf(fminf(fmaxf(rintf(n3*k),-128.f),127.f));
  ((ushort4*)(xq + row*DM))[tid] = q;
  if(!tid) rsx[row] = amaxn*(1.f/127.f);
}

// ---------------- rmsnorm -> act_quant, in-place, D=4096 bf16 rows ----------------
__global__ __launch_bounds__(256)
void rmsq4096(unsigned short* __restrict__ z, float* __restrict__ rsx){
  __shared__ float s1[4], s2[4];
  const int tid = threadIdx.x;
  unsigned short* zr = z + (size_t)blockIdx.x*4096;
  float v[16];
  #pragma unroll
  for(int i=0;i<4;i++){
    ushort4 u = ((const ushort4*)zr)[tid + i*256];
    v[i*4+0]=bf2f(u.x); v[i*4+1]=bf2f(u.y); v[i*4+2]=bf2f(u.z); v[i*4+3]=bf2f(u.w);
  }
  float ss=0.f, mx=0.f;
  #pragma unroll
  for(int i=0;i<16;i++){ ss += v[i]*v[i]; mx = fmaxf(mx, fabsf(v[i])); }
  blockSumMax(ss, mx, s1, s2);
  float rms   = rsqrtf(ss*(1.f/4096.f) + 1e-6f);
  float amaxn = fmaxf(mx*rms, 1e-5f);
  float k     = rms*127.f/amaxn;
  #pragma unroll
  for(int i=0;i<4;i++){
    ushort4 q;
    q.x = f2bf(fminf(fmaxf(rintf(v[i*4+0]*k),-128.f),127.f));
    q.y = f2bf(fminf(fmaxf(rintf(v[i*4+1]*k),-128.f),127.f));
    q.z = f2bf(fminf(fmaxf(rintf(v[i*4+2]*k),-128.f),127.f));
    q.w = f2bf(fminf(fmaxf(rintf(v[i*4+3]*k),-128.f),127.f));
    ((ushort4*)zr)[tid + i*256] = q;
  }
  if(!tid) rsx[blockIdx.x] = amaxn*(1.f/127.f);
}

// ---------------- HGRN chunked scan ----------------
__global__ __launch_bounds__(256)
void scan_pass1(const unsigned short* __restrict__ ir, const unsigned short* __restrict__ fr,
                float* __restrict__ A, float* __restrict__ B){
  int c = blockIdx.x, b = blockIdx.y;
  int d0 = threadIdx.x*4;
  size_t base = ((size_t)b*SJ + (size_t)c*TCH)*DM + d0;
  float a0=1,a1=1,a2=1,a3=1, h0=0,h1=0,h2=0,h3=0;
  #pragma unroll
  for(int t=0;t<TCH;t++){
    ushort4 iv = *(const ushort4*)(ir + base + (size_t)t*DM);
    ushort4 fv = *(const ushort4*)(fr + base + (size_t)t*DM);
    float f0=sigm(bf2f(fv.x)), f1=sigm(bf2f(fv.y)), f2=sigm(bf2f(fv.z)), f3=sigm(bf2f(fv.w));
    float x0=bf2f(iv.x), x1=bf2f(iv.y), x2=bf2f(iv.z), x3=bf2f(iv.w);
    float p0=x0*sigm(x0)*(1.f-f0), p1=x1*sigm(x1)*(1.f-f1);
    float p2=x2*sigm(x2)*(1.f-f2), p3=x3*sigm(x3)*(1.f-f3);
    h0=f0*h0+p0; h1=f1*h1+p1; h2=f2*h2+p2; h3=f3*h3+p3;
    a0*=f0; a1*=f1; a2*=f2; a3*=f3;
  }
  size_t idx = (size_t)c*2048 + b*1024 + d0;
  *(float4*)(A + idx) = make_float4(a0,a1,a2,a3);
  *(float4*)(B + idx) = make_float4(h0,h1,h2,h3);
}

__global__ __launch_bounds__(256)
void scan_pass2(const float* __restrict__ A, const float* __restrict__ B, float* __restrict__ H){
  int chain = blockIdx.x*256 + threadIdx.x;
  float h = 0.f;
  for(int c0=0;c0<NCH;c0+=8){
    float a[8], bb[8];
    #pragma unroll
    for(int u=0;u<8;u++){
      a[u]  = A[(size_t)(c0+u)*2048 + chain];
      bb[u] = B[(size_t)(c0+u)*2048 + chain];
    }
    #pragma unroll
    for(int u=0;u<8;u++){
      H[(size_t)(c0+u)*2048 + chain] = h;
      h = a[u]*h + bb[u];
    }
  }
}

__global__ __launch_bounds__(256)
void scan_pass3(const unsigned short* __restrict__ ir, const unsigned short* __restrict__ fr,
                const float* __restrict__ H, unsigned short* __restrict__ o){
  int c = blockIdx.x, b = blockIdx.y;
  int d0 = threadIdx.x*4;
  size_t base = ((size_t)b*SJ + (size_t)c*TCH)*DM + d0;
  float4 hv = *(const float4*)(H + (size_t)c*2048 + b*1024 + d0);
  float h0=hv.x, h1=hv.y, h2=hv.z, h3=hv.w;
  #pragma unroll
  for(int t=0;t<TCH;t++){
    ushort4 iv = *(const ushort4*)(ir + base + (size_t)t*DM);
    ushort4 fv = *(const ushort4*)(fr + base + (size_t)t*DM);
    float f0=sigm(bf2f(fv.x)), f1=sigm(bf2f(fv.y)), f2=sigm(bf2f(fv.z)), f3=sigm(bf2f(fv.w));
    float x0=bf2f(iv.x), x1=bf2f(iv.y), x2=bf2f(iv.z), x3=bf2f(iv.w);
    float p0=x0*sigm(x0)*(1.f-f0), p1=x1*sigm(x1)*(1.f-f1);
    float p2=x2*sigm(x2)*(1.f-f2), p3=x3*sigm(x3)*(1.f-f3);
    h0=f0*h0+p0; h1=f1*h1+p1; h2=f2*h2+p2; h3=f3*h3+p3;
    ushort4 ov; ov.x=f2bf(h0); ov.y=f2bf(h1); ov.z=f2bf(h2); ov.w=f2bf(h3);
    *(ushort4*)(o + base + (size_t)t*DM) = ov;
  }
}

// ---------------- epilogue ids ----------------
#define EPI_IFG    0
#define EPI_WO     1
#define EPI_GLU    2
#define EPI_RESID  3
#define EPI_RESIDA 4

struct GemmP {
  const float* rsx;
  const float* swinv;
  unsigned short* outb;
  float* outf;
  const float* resid;
  const float* egate;
  int bshift;
  const unsigned short* w2;
  const float* eh; const float* ec;
  const float* hid; const float* enc;
  float* out_h; float* out_c; float* out_c2;
};

// ================== 8-phase 256-row pipelined GEMM ==================
// VAR 0: BN=256 single-B | VAR 1: BN=128 dual-B (fused GLU) | VAR 2: BN=128 single-B
template<int VAR, int EPI>
__global__ __launch_bounds__(512, 2)
void gemm8(const unsigned short* __restrict__ Aq, const unsigned short* __restrict__ Bq,
           int Ncols, int K, int lda, GemmP p){
  constexpr int BBYT = (VAR==2)? 16384 : 32768;   // B bytes per K-tile
  constexpr int TB   = 32768 + BBYT;              // tile bytes
  constexpr int NF   = (VAR==0)? 4 : 2;           // B n-frags per wave (per matrix)
  constexpr int BN   = (VAR==0)? 256 : 128;
  __shared__ char lds[2*TB];

  const int tid = threadIdx.x, wv = tid>>6, lane = tid&63;
  const int wm = wv>>2, wn = wv&3;
  const int nwg = gridDim.x*gridDim.y;
  const int id  = blockIdx.y*gridDim.x + blockIdx.x;
  const int wg  = (id&7)*(nwg>>3) + (id>>3);
  const int nb  = wg % gridDim.x, mb = wg / gridDim.x;

  // staging (pre-swizzled global source -> linear LDS): LDS[row][ch] = G[row][ch ^ (row&7)]
  const int srow = wv*8 + (lane>>3);
  const int sch  = ((lane&7) ^ (lane>>3))*8;   // elems
  const unsigned short* ag = Aq + (size_t)(mb*256 + srow)*lda + sch;
  const unsigned short* bg1 = Bq + (size_t)(nb*BN + srow)*lda + sch;
  const unsigned short* bg2 = nullptr;
  if constexpr (VAR==1) bg2 = p.w2 + (size_t)(nb*128 + srow)*lda + sch;
  const int wvoff = wv*1024;   // 8 rows * 128B per wave within each 64-row region

  auto stageA = [&](char* bufn, int rb, int k0){
    gl_lds16(ag + (size_t)rb*lda + k0, bufn + rb*128 + wvoff);
  };
  auto stageB = [&](char* bufn, int rb, int k0, int m2){
    const unsigned short* src = m2 ? bg2 : bg1;
    gl_lds16(src + (size_t)rb*lda + k0, bufn + 32768 + m2*16384 + rb*128 + wvoff);
  };
  auto stagePh = [&](int ph, char* bufn, int kn){
    if constexpr (VAR==0){
      if(ph==0){ stageB(bufn,0,kn,0);   stageB(bufn,64,kn,0); }
      else if(ph==1){ stageB(bufn,128,kn,0); stageB(bufn,192,kn,0); }
      else if(ph==2){ stageA(bufn,0,kn);   stageA(bufn,128,kn); }
      else          { stageA(bufn,64,kn);  stageA(bufn,192,kn); }
    } else if constexpr (VAR==1){
      if(ph==0){ stageB(bufn,0,kn,0);  stageB(bufn,64,kn,0); }
      else if(ph==1){ stageB(bufn,0,kn,1);  stageB(bufn,64,kn,1); }
      else if(ph==2){ stageA(bufn,0,kn);   stageA(bufn,128,kn); }
      else          { stageA(bufn,64,kn);  stageA(bufn,192,kn); }
    } else {
      if(ph==0){ stageB(bufn,0,kn,0);  stageB(bufn,64,kn,0); }
      else if(ph==1){ stageA(bufn,0,kn);   stageA(bufn,128,kn); }
      else if(ph==2){ stageA(bufn,64,kn);  stageA(bufn,192,kn); }
      // ph==3: none
    }
  };

  // fragment read addressing (swizzled)
  const int lr = lane&15;
  const int kq = lane>>4;
  const int axor = (lr&7)<<4;
  const int col0 = (kq<<4) ^ axor;          // kk=0 byte col
  const int col1 = (64 | (kq<<4)) ^ axor;   // kk=1
  const int arowb = (wm*128 + lr)*128;
  const int browb = ((VAR==0? wn*64 : wn*32) + lr)*128;

  f32x4 acc[8][NF];
  f32x4 acc2[(VAR==1)?8:1][NF];
  #pragma unroll
  for(int i=0;i<8;i++)
    #pragma unroll
    for(int j=0;j<NF;j++){ acc[i][j]=(f32x4){0,0,0,0}; if constexpr(VAR==1) acc2[i][j]=(f32x4){0,0,0,0}; }

  bf16x8 breg[NF], breg2[(VAR==1)?NF:1];

  auto phase = [&](char* bufc, int ph, char* bufn, int kn, bool doStage){
    const int colb = (ph>>1)? col1 : col0;
    const int mh = ph&1;
    if(mh==0){
      #pragma unroll
      for(int nf=0;nf<NF;nf++)
        breg[nf] = *(const bf16x8*)(bufc + 32768 + browb + nf*2048 + colb);
      if constexpr (VAR==1){
        #pragma unroll
        for(int nf=0;nf<NF;nf++)
          breg2[nf] = *(const bf16x8*)(bufc + 32768 + 16384 + browb + nf*2048 + colb);
      }
    }
    bf16x8 areg[4];
    #pragma unroll
    for(int i=0;i<4;i++)
      areg[i] = *(const bf16x8*)(bufc + arowb + (mh*4+i)*2048 + colb);
    if(doStage) stagePh(ph, bufn, kn);
    __builtin_amdgcn_s_setprio(1);
    #pragma unroll
    for(int i=0;i<4;i++){
      #pragma unroll
      for(int nf=0;nf<NF;nf++){
        acc[mh*4+i][nf] = __builtin_amdgcn_mfma_f32_16x16x32_bf16(areg[i], breg[nf], acc[mh*4+i][nf], 0,0,0);
        if constexpr (VAR==1)
          acc2[mh*4+i][nf] = __builtin_amdgcn_mfma_f32_16x16x32_bf16(areg[i], breg2[nf], acc2[mh*4+i][nf], 0,0,0);
      }
    }
    __builtin_amdgcn_s_setprio(0);
  };

  #define VMW2 asm volatile("s_waitcnt vmcnt(2)" ::: "memory")
  #define VMW0 asm volatile("s_waitcnt vmcnt(0)" ::: "memory")
  #define BARR { __builtin_amdgcn_s_barrier(); __builtin_amdgcn_sched_barrier(0); }

  // prologue: stage tile 0 in L-order
  stagePh(0, lds, 0); stagePh(1, lds, 0); stagePh(2, lds, 0); stagePh(3, lds, 0);

  const int NT = K>>6;
  for(int t=0; t<NT-1; ++t){
    char* bufc = lds + (t&1)*TB;
    char* bufn = lds + ((t+1)&1)*TB;
    const int kn = (t+1)<<6;
    VMW2; BARR; phase(bufc, 0, bufn, kn, true);
    VMW2; BARR; phase(bufc, 1, bufn, kn, true);
          BARR; phase(bufc, 2, bufn, kn, true);
          BARR; phase(bufc, 3, bufn, kn, true);
  }
  { // epilogue K-tile
    char* bufc = lds + ((NT-1)&1)*TB;
    VMW2; BARR; phase(bufc, 0, nullptr, 0, false);
    VMW0; BARR; phase(bufc, 1, nullptr, 0, false);
          BARR; phase(bufc, 2, nullptr, 0, false);
          BARR; phase(bufc, 3, nullptr, 0, false);
  }

  // ---- C write ----
  float sw;
  if constexpr (EPI==EPI_IFG) sw = p.swinv[(nb*256)>>10];
  else                        sw = *p.swinv;
  const int r0 = mb*256 + wm*128;
  const int c0 = nb*BN + wn*((VAR==0)?64:32);
  #pragma unroll
  for(int mf=0;mf<8;mf++){
    #pragma unroll
    for(int j=0;j<4;j++){
      int r = r0 + mf*16 + kq*4 + j;
      float rs = p.rsx[r]*sw;
      #pragma unroll
      for(int nf=0;nf<NF;nf++){
        int c = c0 + nf*16 + lr;
        float val = acc[mf][nf][j]*rs;
        if constexpr (EPI==EPI_IFG){
          int mat = c >> 10;
          p.outb[(size_t)mat*9437184 + (size_t)r*1024 + (c&1023)] = f2bf(val);
        } else if constexpr (EPI==EPI_GLU){
          float v2 = acc2[mf][nf][j]*rs;
          p.outb[(size_t)r*Ncols + c] = f2bf(val*sigm(val)*v2);
        } else if constexpr (EPI==EPI_RESID){
          int b = r >> p.bshift;
          size_t idx = (size_t)r*DM + c;
          p.outf[idx] = p.resid[idx] + p.egate[b*6144 + 5*1024 + c]*val;
        } else { // EPI_WO
          int b = r / SJ; int s = r - b*SJ;
          if (s < SCTX){
            size_t idx = ((size_t)b*SCTX + s)*DM + c;
            float ov = p.enc[idx] + p.ec[b*6144 + 2*1024 + c]*val;
            p.out_c[idx]  = ov;
            p.out_c2[idx] = ov;
          } else {
            size_t idx = ((size_t)b*SIMG + (s-SCTX))*DM + c;
            p.out_h[idx] = p.hid[idx] + p.eh[b*6144 + 2*1024 + c]*val;
          }
        }
      }
    }
  }
  #undef VMW2
  #undef VMW0
  #undef BARR
}

// ---------------- old 2-phase GEMM (kept for small ctx down-proj, split-K atomic) ----------------
__global__ __launch_bounds__(256, 2)
void gemm_bt_ra(const unsigned short* __restrict__ Aq, const unsigned short* __restrict__ Wq,
                int K, int lda, GemmP p){
  __shared__ unsigned short As[128*64];
  __shared__ unsigned short Bs[128*64];
  const int tid = threadIdx.x;
  const int wave = tid>>6, lane = tid&63;
  const int nwg = gridDim.x*gridDim.y;
  const int id  = blockIdx.y*gridDim.x + blockIdx.x;
  const int wg  = (id&7)*(nwg>>3) + (id>>3);
  const int nb  = wg % gridDim.x, mb = wg / gridDim.x;
  const int wr = wave>>1, wc = wave&1;
  const int koff = blockIdx.z*K;

  const int grow = wave*8 + (lane>>3);
  const int gcol = (lane&7)*8;
  const unsigned short* ag = Aq + (size_t)(mb*128 + grow)*lda + koff + gcol;
  const unsigned short* bg = Wq + (size_t)(nb*128 + grow)*lda + koff + gcol;
  char* asl = (char*)As + wave*1024;
  char* bsl = (char*)Bs + wave*1024;

  f32x4 acc[4][4];
  #pragma unroll
  for(int i=0;i<4;i++)
    #pragma unroll
    for(int j=0;j<4;j++) acc[i][j] = (f32x4){0.f,0.f,0.f,0.f};

  const int lrow = lane&15, lk8 = (lane>>4)*8;
  const unsigned short* arow = &As[(wr*64 + lrow)*64 + lk8];
  const unsigned short* brow = &Bs[(wc*64 + lrow)*64 + lk8];

  for(int k0=0; k0<K; k0+=64){
    #pragma unroll
    for(int pp=0;pp<4;pp++){
      gl_lds16(ag + (size_t)pp*32*lda + k0, asl + pp*4096);
      gl_lds16(bg + (size_t)pp*32*lda + k0, bsl + pp*4096);
    }
    __syncthreads();
    #pragma unroll
    for(int kk=0;kk<2;kk++){
      bf16x8 af[4], bfr[4];
      #pragma unroll
      for(int m=0;m<4;m++) af[m]  = *(const bf16x8*)(arow + m*1024 + kk*32);
      #pragma unroll
      for(int n=0;n<4;n++) bfr[n] = *(const bf16x8*)(brow + n*1024 + kk*32);
      #pragma unroll
      for(int m=0;m<4;m++)
        #pragma unroll
        for(int n=0;n<4;n++)
          acc[m][n] = __builtin_amdgcn_mfma_f32_16x16x32_bf16(af[m], bfr[n], acc[m][n], 0,0,0);
    }
    __syncthreads();
  }

  const float sw = *p.swinv;
  const int r0 = mb*128 + wr*64, c0 = nb*128 + wc*64;
  #pragma unroll
  for(int m=0;m<4;m++){
    #pragma unroll
    for(int j=0;j<4;j++){
      int r = r0 + m*16 + ((lane>>4)<<2) + j;
      float rs = p.rsx[r]*sw;
      #pragma unroll
      for(int n=0;n<4;n++){
        int c = c0 + n*16 + (lane&15);
        float val = acc[m][n][j]*rs;
        int b = r >> p.bshift;
        size_t idx = (size_t)r*DM + c;
        atomicAdd(&p.outf[idx], p.egate[b*6144 + 5*1024 + c]*val);
      }
    }
  }
}

// ================= host =================
extern "C" void kernel_launch(void* const* d_in, const int* in_sizes, int n_in,
                              void* d_out, int out_size, void* d_ws, size_t ws_size,
                              hipStream_t stream){
  (void)in_sizes; (void)n_in; (void)out_size; (void)ws_size;
  const float* hidden   = (const float*)d_in[0];
  const float* enc      = (const float*)d_in[1];
  const float* temb     = (const float*)d_in[2];
  const float* adaln_w  = (const float*)d_in[3];
  const float* adaln_b  = (const float*)d_in[4];
  const float* adaln_cw = (const float*)d_in[5];
  const float* adaln_cb = (const float*)d_in[6];
  const float* wi  = (const float*)d_in[7];
  const float* wf  = (const float*)d_in[8];
  const float* wg  = (const float*)d_in[9];
  const float* wo  = (const float*)d_in[10];
  const float* gnw = (const float*)d_in[11];
  const float* ffg = (const float*)d_in[12];
  const float* ffd = (const float*)d_in[13];
  const float* fcg = (const float*)d_in[14];
  const float* fcd = (const float*)d_in[15];

  const size_t MB = 1024ull*1024ull;
  char* ws = (char*)d_ws;
  unsigned short* WQ_WI  = (unsigned short*)(ws + 0*MB);
  unsigned short* WQ_WF  = (unsigned short*)(ws + 2*MB);
  unsigned short* WQ_WG  = (unsigned short*)(ws + 4*MB);
  unsigned short* WQ_WO  = (unsigned short*)(ws + 6*MB);
  unsigned short* WQ_FFG = (unsigned short*)(ws + 8*MB);
  unsigned short* WQ_FFD = (unsigned short*)(ws + 24*MB);
  unsigned short* WQ_FCG = (unsigned short*)(ws + 32*MB);
  unsigned short* WQ_FCD = (unsigned short*)(ws + 48*MB);
  float* PART  = (float*)(ws + 56*MB);
  float* SWINV = (float*)(ws + 56*MB + 32*1024);
  float* EH    = (float*)(ws + 56*MB + 64*1024);
  float* EC    = (float*)(ws + 56*MB + 112*1024);
  float* RSX1  = (float*)(ws + 56*MB + 160*1024);
  float* RSX2  = (float*)(ws + 56*MB + 200*1024);
  float* RSX3  = (float*)(ws + 56*MB + 240*1024);
  float* RSXZ  = (float*)(ws + 56*MB + 280*1024);
  float* RSX4  = (float*)(ws + 56*MB + 320*1024);
  float* RSXZC = (float*)(ws + 56*MB + 328*1024);
  float* SCANA = (float*)(ws + 57*MB);
  float* SCANB = (float*)(ws + 61*MB);
  float* SCANH = (float*)(ws + 65*MB);
  unsigned short* XQ   = (unsigned short*)(ws + 70*MB);
  unsigned short* IRAW = (unsigned short*)(ws + 89*MB);
  unsigned short* FRAW = (unsigned short*)(ws + 107*MB);
  unsigned short* GRAW = (unsigned short*)(ws + 125*MB);
  unsigned short* OBUF = (unsigned short*)(ws + 143*MB);
  float* HNEW = (float*)(ws + 165*MB);
  unsigned short* SG = (unsigned short*)(ws + 89*MB);
  float* CNEW = (float*)(ws + 199*MB);
  float* OUT_H = (float*)d_out;
  float* OUT_C = (float*)d_out + 8388608;

  // ---- weight quantization ----
  WList L;
  L.w[0]=wi;  L.n[0]=1048576ull; L.q[0]=WQ_WI;
  L.w[1]=wf;  L.n[1]=1048576ull; L.q[1]=WQ_WF;
  L.w[2]=wg;  L.n[2]=1048576ull; L.q[2]=WQ_WG;
  L.w[3]=wo;  L.n[3]=1048576ull; L.q[3]=WQ_WO;
  L.w[4]=ffg; L.n[4]=8388608ull; L.q[4]=WQ_FFG;
  L.w[5]=ffd; L.n[5]=4194304ull; L.q[5]=WQ_FFD;
  L.w[6]=fcg; L.n[6]=8388608ull; L.q[6]=WQ_FCG;
  L.w[7]=fcd; L.n[7]=4194304ull; L.q[7]=WQ_FCD;
  wq_reduce  <<<dim3(512,8), 256, 0, stream>>>(L, PART);
  wq_finalize<<<8,          256, 0, stream>>>(L, PART, SWINV);
  wq_quant   <<<dim3(1024,8),256, 0, stream>>>(L, SWINV);

  // ---- adaLN embeddings ----
  adaln_gemv<<<dim3(1536,2), 256, 0, stream>>>(temb, adaln_w,  adaln_b,  EH);
  adaln_gemv<<<dim3(1536,2), 256, 0, stream>>>(temb, adaln_cw, adaln_cb, EC);

  // ---- joint = [adaLN(enc); adaLN(hidden)], rmsnorm+quant ----
  modnorm_quant<<<1024, 256, 0, stream>>>(enc,    9,  EC, 0, 1024, XQ, RSX1, 0,   SJ);
  modnorm_quant<<<8192, 256, 0, stream>>>(hidden, 12, EH, 0, 1024, XQ, RSX1, 512, SJ);

  // ---- merged i/f/g bitlinear (N=3072), 8-phase ----
  GemmP p{};
  p.rsx = RSX1; p.swinv = SWINV; p.outb = IRAW;
  gemm8<0,EPI_IFG><<<dim3(12,36), 512, 0, stream>>>(XQ, WQ_WI, 3072, 1024, 1024, p);

  // ---- HGRN scan ----
  scan_pass1<<<dim3(NCH,2), 256, 0, stream>>>(IRAW, FRAW, SCANA, SCANB);
  scan_pass2<<<8,           256, 0, stream>>>(SCANA, SCANB, SCANH);
  scan_pass3<<<dim3(NCH,2), 256, 0, stream>>>(IRAW, FRAW, SCANH, OBUF);

  // ---- gnorm + gate + quant ----
  gnorm_quant<<<9216, 256, 0, stream>>>(OBUF, GRAW, gnw, XQ, RSX2);

  // ---- wo bitlinear with gated residual split (also pre-fills OUT_C) ----
  GemmP pw{};
  pw.rsx = RSX2; pw.swinv = SWINV+3;
  pw.eh = EH; pw.ec = EC; pw.hid = hidden; pw.enc = enc;
  pw.out_h = HNEW; pw.out_c = CNEW; pw.out_c2 = OUT_C;
  gemm8<2,EPI_WO><<<dim3(8,36), 512, 0, stream>>>(XQ, WQ_WO, 1024, 1024, 1024, pw);

  // ---- image MLP ----
  modnorm_quant<<<8192, 256, 0, stream>>>(HNEW, 12, EH, 3*1024, 4*1024, XQ, RSX3, 0, SIMG);
  GemmP pg{};
  pg.rsx = RSX3; pg.swinv = SWINV+4; pg.outb = SG; pg.w2 = WQ_FFG + (size_t)4096*1024;
  gemm8<1,EPI_GLU><<<dim3(32,32), 512, 0, stream>>>(XQ, WQ_FFG, 4096, 1024, 1024, pg);
  rmsq4096<<<8192, 256, 0, stream>>>(SG, RSXZ);
  GemmP pd{};
  pd.rsx = RSXZ; pd.swinv = SWINV+5; pd.outf = OUT_H; pd.resid = HNEW; pd.egate = EH; pd.bshift = 12;
  gemm8<2,EPI_RESID><<<dim3(8,32), 512, 0, stream>>>(SG, WQ_FFD, 1024, 4096, 4096, pd);

  // ---- context MLP ----
  modnorm_quant<<<1024, 256, 0, stream>>>(CNEW, 9, EC, 3*1024, 4*1024, XQ, RSX4, 0, SCTX);
  GemmP pc{};
  pc.rsx = RSX4; pc.swinv = SWINV+6; pc.outb = SG; pc.w2 = WQ_FCG + (size_t)4096*1024;
  gemm8<1,EPI_GLU><<<dim3(32,4), 512, 0, stream>>>(XQ, WQ_FCG, 4096, 1024, 1024, pc);
  rmsq4096<<<1024, 256, 0, stream>>>(SG, RSXZC);
  GemmP pe{};
  pe.rsx = RSXZC; pe.swinv = SWINV+7; pe.outf = OUT_C; pe.egate = EC; pe.bshift = 9;
  gemm_bt_ra<<<dim3(8,8,4), 256, 0, stream>>>(SG, WQ_FCD, 1024, 4096, pe);
}

// Round 4
// 511.401 us; speedup vs baseline: 1.8433x; 1.3012x over previous
//
#include <hip/hip_runtime.h>
#include <hip/hip_bf16.h>
#include <stdint.h>

#define DM   1024
#define SJ   4608
#define SCTX 512
#define SIMG 4096
#define NCH  512
#define TCH  9

typedef __attribute__((ext_vector_type(4))) int   i32x4;
typedef __attribute__((ext_vector_type(4))) float f32x4;

__device__ __forceinline__ float bf2f(unsigned short u){
  union { unsigned int i; float f; } v; v.i = ((unsigned int)u) << 16; return v.f;
}
__device__ __forceinline__ unsigned short f2bf(float f){
  unsigned int u = __float_as_uint(f);
  u += 0x7fffu + ((u >> 16) & 1u);
  return (unsigned short)(u >> 16);
}
__device__ __forceinline__ float sigm(float x){ return 1.f/(1.f+__expf(-x)); }
__device__ __forceinline__ signed char q8(float v, float lo, float hi){
  return (signed char)(int)fminf(fmaxf(rintf(v),lo),hi);
}

__device__ __forceinline__ float wsum(float v){
  #pragma unroll
  for(int o=32;o>0;o>>=1) v += __shfl_xor(v,o);
  return v;
}
__device__ __forceinline__ float wmax(float v){
  #pragma unroll
  for(int o=32;o>0;o>>=1) v = fmaxf(v,__shfl_xor(v,o));
  return v;
}
__device__ __forceinline__ void blockSumSum(float& a, float& b, float* s1, float* s2){
  a = wsum(a); b = wsum(b);
  if(!(threadIdx.x&63)){ s1[threadIdx.x>>6]=a; s2[threadIdx.x>>6]=b; }
  __syncthreads();
  a = s1[0]+s1[1]+s1[2]+s1[3];
  b = s2[0]+s2[1]+s2[2]+s2[3];
  __syncthreads();
}
__device__ __forceinline__ void blockSumMax(float& a, float& b, float* s1, float* s2){
  a = wsum(a); b = wmax(b);
  if(!(threadIdx.x&63)){ s1[threadIdx.x>>6]=a; s2[threadIdx.x>>6]=b; }
  __syncthreads();
  a = s1[0]+s1[1]+s1[2]+s1[3];
  b = fmaxf(fmaxf(s2[0],s2[1]),fmaxf(s2[2],s2[3]));
  __syncthreads();
}

// ---------------- async global->LDS ----------------
typedef __attribute__((address_space(1))) void gvoid_t;
typedef __attribute__((address_space(3))) void lvoid_t;
__device__ __forceinline__ void gl_lds16(const void* g, void* l){
  __builtin_amdgcn_global_load_lds((gvoid_t*)g, (lvoid_t*)l, 16, 0, 0);
}

// ---------------- weight quantization ----------------
struct WList {
  const float* w[8];
  unsigned long long n[8];
  signed char* q[8];
};

__global__ __launch_bounds__(256)
void wq_reduce(WList L, float* __restrict__ part){
  __shared__ float s1[4];
  int m = blockIdx.y;
  const float4* w4 = (const float4*)L.w[m];
  size_t n4 = L.n[m] >> 2;
  float s = 0.f;
  for(size_t i = (size_t)blockIdx.x*256 + threadIdx.x; i < n4; i += (size_t)512*256){
    float4 v = w4[i];
    s += fabsf(v.x)+fabsf(v.y)+fabsf(v.z)+fabsf(v.w);
  }
  s = wsum(s);
  if(!(threadIdx.x&63)) s1[threadIdx.x>>6] = s;
  __syncthreads();
  if(!threadIdx.x) part[m*512 + blockIdx.x] = s1[0]+s1[1]+s1[2]+s1[3];
}

__global__ __launch_bounds__(256)
void wq_finalize(WList L, const float* __restrict__ part, float* __restrict__ swinv){
  __shared__ float s1[4];
  int m = blockIdx.x;
  float s = part[m*512 + threadIdx.x] + part[m*512 + 256 + threadIdx.x];
  s = wsum(s);
  if(!(threadIdx.x&63)) s1[threadIdx.x>>6] = s;
  __syncthreads();
  if(!threadIdx.x){
    float mean = (s1[0]+s1[1]+s1[2]+s1[3]) / (float)L.n[m];
    swinv[m] = fmaxf(mean, 1e-5f);
  }
}

__global__ __launch_bounds__(256)
void wq_quant(WList L, const float* __restrict__ swinv){
  int m = blockIdx.y;
  float sc = 1.f / swinv[m];
  const float4* w4 = (const float4*)L.w[m];
  signed char* q = L.q[m];
  size_t n4 = L.n[m] >> 2;
  for(size_t i = (size_t)blockIdx.x*256 + threadIdx.x; i < n4; i += (size_t)1024*256){
    float4 v = w4[i];
    char4 o;
    o.x = q8(v.x*sc,-1.f,1.f);
    o.y = q8(v.y*sc,-1.f,1.f);
    o.z = q8(v.z*sc,-1.f,1.f);
    o.w = q8(v.w*sc,-1.f,1.f);
    ((char4*)q)[i] = o;
  }
}

// ---------------- adaLN embedding GEMV ----------------
__global__ __launch_bounds__(256)
void adaln_gemv(const float* __restrict__ temb, const float* __restrict__ W,
                const float* __restrict__ bias, float* __restrict__ e){
  int o = blockIdx.x*4 + (threadIdx.x>>6);
  int b = blockIdx.y;
  int lane = threadIdx.x & 63;
  const float4* t4 = (const float4*)(temb + b*DM);
  const float4* w4 = (const float4*)(W + (size_t)o*DM);
  float acc = 0.f;
  #pragma unroll
  for(int i=0;i<4;i++){
    float4 tv = t4[i*64+lane], wv = w4[i*64+lane];
    acc += (tv.x*sigm(tv.x))*wv.x + (tv.y*sigm(tv.y))*wv.y
         + (tv.z*sigm(tv.z))*wv.z + (tv.w*sigm(tv.w))*wv.w;
  }
  acc = wsum(acc);
  if(!lane) e[b*6144 + o] = acc + bias[o];
}

// ---------------- LN -> adaLN modulate -> rmsnorm -> act_quant (int8) ----------------
__global__ __launch_bounds__(256)
void modnorm_quant(const float* __restrict__ x, int bshift,
                   const float* __restrict__ e, int scaleOff, int shiftOff,
                   signed char* __restrict__ xq, float* __restrict__ rsx,
                   int outRowOff, int outBatchStride){
  __shared__ float s1[4], s2[4];
  const int tid = threadIdx.x;
  const int row = blockIdx.x;
  const int b = row >> bshift, s = row & ((1<<bshift)-1);
  float4 xv = ((const float4*)(x + (size_t)row*DM))[tid];
  float sum = xv.x+xv.y+xv.z+xv.w;
  float ss  = xv.x*xv.x+xv.y*xv.y+xv.z*xv.z+xv.w*xv.w;
  blockSumSum(sum, ss, s1, s2);
  float mu  = sum * (1.f/DM);
  float inv = rsqrtf(ss*(1.f/DM) - mu*mu + 1e-6f);
  float4 scv = ((const float4*)(e + b*6144 + scaleOff))[tid];
  float4 shv = ((const float4*)(e + b*6144 + shiftOff))[tid];
  float n0 = (xv.x-mu)*inv*(1.f+scv.x)+shv.x;
  float n1 = (xv.y-mu)*inv*(1.f+scv.y)+shv.y;
  float n2 = (xv.z-mu)*inv*(1.f+scv.z)+shv.z;
  float n3 = (xv.w-mu)*inv*(1.f+scv.w)+shv.w;
  float ss2 = n0*n0+n1*n1+n2*n2+n3*n3;
  float mx  = fmaxf(fmaxf(fabsf(n0),fabsf(n1)),fmaxf(fabsf(n2),fabsf(n3)));
  blockSumMax(ss2, mx, s1, s2);
  float rms   = rsqrtf(ss2*(1.f/DM) + 1e-6f);
  float amaxn = fmaxf(mx*rms, 1e-5f);
  float k     = rms*127.f/amaxn;
  int orow = b*outBatchStride + outRowOff + s;
  char4 q;
  q.x = q8(n0*k,-128.f,127.f);
  q.y = q8(n1*k,-128.f,127.f);
  q.z = q8(n2*k,-128.f,127.f);
  q.w = q8(n3*k,-128.f,127.f);
  ((char4*)(xq + (size_t)orow*DM))[tid] = q;
  if(!tid) rsx[orow] = amaxn*(1.f/127.f);
}

// ---------------- rmsnorm(o)*gnw*silu(g) -> rmsnorm -> act_quant (int8) ----------------
__global__ __launch_bounds__(256)
void gnorm_quant(const unsigned short* __restrict__ o, const unsigned short* __restrict__ g,
                 const float* __restrict__ gnw,
                 signed char* __restrict__ xq, float* __restrict__ rsx){
  __shared__ float s1[4], s2[4];
  const int tid = threadIdx.x;
  const size_t row = blockIdx.x;
  ushort4 ov = ((const ushort4*)(o + row*DM))[tid];
  ushort4 gv = ((const ushort4*)(g + row*DM))[tid];
  float o0=bf2f(ov.x), o1=bf2f(ov.y), o2=bf2f(ov.z), o3=bf2f(ov.w);
  float g0=bf2f(gv.x), g1=bf2f(gv.y), g2=bf2f(gv.z), g3=bf2f(gv.w);
  float ss = o0*o0+o1*o1+o2*o2+o3*o3;
  float dummy = 0.f;
  blockSumSum(ss, dummy, s1, s2);
  float rms = rsqrtf(ss*(1.f/DM) + 1e-6f);
  float4 wv = ((const float4*)gnw)[tid];
  float n0 = o0*rms*wv.x*(g0*sigm(g0));
  float n1 = o1*rms*wv.y*(g1*sigm(g1));
  float n2 = o2*rms*wv.z*(g2*sigm(g2));
  float n3 = o3*rms*wv.w*(g3*sigm(g3));
  float ss2 = n0*n0+n1*n1+n2*n2+n3*n3;
  float mx  = fmaxf(fmaxf(fabsf(n0),fabsf(n1)),fmaxf(fabsf(n2),fabsf(n3)));
  blockSumMax(ss2, mx, s1, s2);
  float rms2  = rsqrtf(ss2*(1.f/DM) + 1e-6f);
  float amaxn = fmaxf(mx*rms2, 1e-5f);
  float k     = rms2*127.f/amaxn;
  char4 q;
  q.x = q8(n0*k,-128.f,127.f);
  q.y = q8(n1*k,-128.f,127.f);
  q.z = q8(n2*k,-128.f,127.f);
  q.w = q8(n3*k,-128.f,127.f);
  ((char4*)(xq + row*DM))[tid] = q;
  if(!tid) rsx[row] = amaxn*(1.f/127.f);
}

// ---------------- rmsnorm -> act_quant, bf16 D=4096 rows -> int8 ----------------
__global__ __launch_bounds__(256)
void rmsq4096(const unsigned short* __restrict__ z, signed char* __restrict__ zq,
              float* __restrict__ rsx){
  __shared__ float s1[4], s2[4];
  const int tid = threadIdx.x;
  const unsigned short* zr = z + (size_t)blockIdx.x*4096;
  signed char* qr = zq + (size_t)blockIdx.x*4096;
  float v[16];
  #pragma unroll
  for(int i=0;i<4;i++){
    ushort4 u = ((const ushort4*)zr)[tid + i*256];
    v[i*4+0]=bf2f(u.x); v[i*4+1]=bf2f(u.y); v[i*4+2]=bf2f(u.z); v[i*4+3]=bf2f(u.w);
  }
  float ss=0.f, mx=0.f;
  #pragma unroll
  for(int i=0;i<16;i++){ ss += v[i]*v[i]; mx = fmaxf(mx, fabsf(v[i])); }
  blockSumMax(ss, mx, s1, s2);
  float rms   = rsqrtf(ss*(1.f/4096.f) + 1e-6f);
  float amaxn = fmaxf(mx*rms, 1e-5f);
  float k     = rms*127.f/amaxn;
  #pragma unroll
  for(int i=0;i<4;i++){
    char4 q;
    q.x = q8(v[i*4+0]*k,-128.f,127.f);
    q.y = q8(v[i*4+1]*k,-128.f,127.f);
    q.z = q8(v[i*4+2]*k,-128.f,127.f);
    q.w = q8(v[i*4+3]*k,-128.f,127.f);
    ((char4*)qr)[tid + i*256] = q;
  }
  if(!tid) rsx[blockIdx.x] = amaxn*(1.f/127.f);
}

// ---------------- HGRN chunked scan ----------------
__global__ __launch_bounds__(256)
void scan_pass1(const unsigned short* __restrict__ ir, const unsigned short* __restrict__ fr,
                float* __restrict__ A, float* __restrict__ B){
  int c = blockIdx.x, b = blockIdx.y;
  int d0 = threadIdx.x*4;
  size_t base = ((size_t)b*SJ + (size_t)c*TCH)*DM + d0;
  float a0=1,a1=1,a2=1,a3=1, h0=0,h1=0,h2=0,h3=0;
  #pragma unroll
  for(int t=0;t<TCH;t++){
    ushort4 iv = *(const ushort4*)(ir + base + (size_t)t*DM);
    ushort4 fv = *(const ushort4*)(fr + base + (size_t)t*DM);
    float f0=sigm(bf2f(fv.x)), f1=sigm(bf2f(fv.y)), f2=sigm(bf2f(fv.z)), f3=sigm(bf2f(fv.w));
    float x0=bf2f(iv.x), x1=bf2f(iv.y), x2=bf2f(iv.z), x3=bf2f(iv.w);
    float p0=x0*sigm(x0)*(1.f-f0), p1=x1*sigm(x1)*(1.f-f1);
    float p2=x2*sigm(x2)*(1.f-f2), p3=x3*sigm(x3)*(1.f-f3);
    h0=f0*h0+p0; h1=f1*h1+p1; h2=f2*h2+p2; h3=f3*h3+p3;
    a0*=f0; a1*=f1; a2*=f2; a3*=f3;
  }
  size_t idx = (size_t)c*2048 + b*1024 + d0;
  *(float4*)(A + idx) = make_float4(a0,a1,a2,a3);
  *(float4*)(B + idx) = make_float4(h0,h1,h2,h3);
}

__global__ __launch_bounds__(256)
void scan_pass2(const float* __restrict__ A, const float* __restrict__ B, float* __restrict__ H){
  int chain = blockIdx.x*256 + threadIdx.x;
  float h = 0.f;
  for(int c0=0;c0<NCH;c0+=8){
    float a[8], bb[8];
    #pragma unroll
    for(int u=0;u<8;u++){
      a[u]  = A[(size_t)(c0+u)*2048 + chain];
      bb[u] = B[(size_t)(c0+u)*2048 + chain];
    }
    #pragma unroll
    for(int u=0;u<8;u++){
      H[(size_t)(c0+u)*2048 + chain] = h;
      h = a[u]*h + bb[u];
    }
  }
}

__global__ __launch_bounds__(256)
void scan_pass3(const unsigned short* __restrict__ ir, const unsigned short* __restrict__ fr,
                const float* __restrict__ H, unsigned short* __restrict__ o){
  int c = blockIdx.x, b = blockIdx.y;
  int d0 = threadIdx.x*4;
  size_t base = ((size_t)b*SJ + (size_t)c*TCH)*DM + d0;
  float4 hv = *(const float4*)(H + (size_t)c*2048 + b*1024 + d0);
  float h0=hv.x, h1=hv.y, h2=hv.z, h3=hv.w;
  #pragma unroll
  for(int t=0;t<TCH;t++){
    ushort4 iv = *(const ushort4*)(ir + base + (size_t)t*DM);
    ushort4 fv = *(const ushort4*)(fr + base + (size_t)t*DM);
    float f0=sigm(bf2f(fv.x)), f1=sigm(bf2f(fv.y)), f2=sigm(bf2f(fv.z)), f3=sigm(bf2f(fv.w));
    float x0=bf2f(iv.x), x1=bf2f(iv.y), x2=bf2f(iv.z), x3=bf2f(iv.w);
    float p0=x0*sigm(x0)*(1.f-f0), p1=x1*sigm(x1)*(1.f-f1);
    float p2=x2*sigm(x2)*(1.f-f2), p3=x3*sigm(x3)*(1.f-f3);
    h0=f0*h0+p0; h1=f1*h1+p1; h2=f2*h2+p2; h3=f3*h3+p3;
    ushort4 ov; ov.x=f2bf(h0); ov.y=f2bf(h1); ov.z=f2bf(h2); ov.w=f2bf(h3);
    *(ushort4*)(o + base + (size_t)t*DM) = ov;
  }
}

// ---------------- epilogue ids ----------------
#define EPI_IFG    0
#define EPI_WO     1
#define EPI_GLU    2
#define EPI_RESID  3

struct GemmP {
  const float* rsx;
  const float* swinv;
  unsigned short* outb;
  float* outf;
  const float* resid;
  const float* egate;
  int bshift;
  const signed char* w2;
  const float* eh; const float* ec;
  const float* hid; const float* enc;
  float* out_h; float* out_c; float* out_c2;
};

// ================== 8-phase 256-row pipelined int8 GEMM, BK=128 ==================
// VAR 0: BN=256 single-B | VAR 1: BN=128 dual-B (fused GLU) | VAR 2: BN=128 single-B
// SWZ 0: row-chunked XCD swizzle | SWZ 1: column-chunked (gx must be 32; 4 nb per XCD)
template<int VAR, int EPI, int SWZ>
__global__ __launch_bounds__(512, 2)
void gemm8(const signed char* __restrict__ Aq, const signed char* __restrict__ Bq,
           int Ncols, int K, int lda, GemmP p){
  constexpr int BBYT = (VAR==2)? 16384 : 32768;
  constexpr int TB   = 32768 + BBYT;
  constexpr int NF   = (VAR==0)? 4 : 2;
  constexpr int BN   = (VAR==0)? 256 : 128;
  __shared__ char lds[2*TB];

  const int tid = threadIdx.x, wv = tid>>6, lane = tid&63;
  const int wm = wv>>2, wn = wv&3;
  const int nwg = gridDim.x*gridDim.y;
  const int id  = blockIdx.y*gridDim.x + blockIdx.x;
  int nb, mb;
  if constexpr (SWZ==1){
    const int x = id&7, j = id>>3;
    nb = x*4 + (j&3);
    mb = j>>2;
  } else {
    const int wg = (id&7)*(nwg>>3) + (id>>3);
    nb = wg % gridDim.x; mb = wg / gridDim.x;
  }

  // staging: pre-swizzled global source -> linear LDS (XOR on 16B units per row&7)
  const int srow = wv*8 + (lane>>3);
  const int sch  = ((lane&7) ^ (lane>>3))*16;   // bytes == elements (i8)
  const signed char* ag  = Aq + (size_t)(mb*256 + srow)*lda + sch;
  const signed char* bg1 = Bq + (size_t)(nb*BN  + srow)*lda + sch;
  const signed char* bg2 = nullptr;
  if constexpr (VAR==1) bg2 = p.w2 + (size_t)(nb*128 + srow)*lda + sch;
  const int wvoff = wv*1024;

  auto stageA = [&](char* bufn, int rb, int k0){
    gl_lds16(ag + (size_t)rb*lda + k0, bufn + rb*128 + wvoff);
  };
  auto stageB = [&](char* bufn, int rb, int k0, int m2){
    const signed char* src = m2 ? bg2 : bg1;
    gl_lds16(src + (size_t)rb*lda + k0, bufn + 32768 + m2*16384 + rb*128 + wvoff);
  };
  auto stagePh = [&](int ph, char* bufn, int kn){
    if constexpr (VAR==0){
      if(ph==0){ stageB(bufn,0,kn,0);   stageB(bufn,64,kn,0); }
      else if(ph==1){ stageB(bufn,128,kn,0); stageB(bufn,192,kn,0); }
      else if(ph==2){ stageA(bufn,0,kn);   stageA(bufn,128,kn); }
      else          { stageA(bufn,64,kn);  stageA(bufn,192,kn); }
    } else if constexpr (VAR==1){
      if(ph==0){ stageB(bufn,0,kn,0);  stageB(bufn,64,kn,0); }
      else if(ph==1){ stageB(bufn,0,kn,1);  stageB(bufn,64,kn,1); }
      else if(ph==2){ stageA(bufn,0,kn);   stageA(bufn,128,kn); }
      else          { stageA(bufn,64,kn);  stageA(bufn,192,kn); }
    } else {
      if(ph==0){ stageB(bufn,0,kn,0);  stageB(bufn,64,kn,0); }
      else if(ph==1){ stageA(bufn,0,kn);   stageA(bufn,128,kn); }
      else if(ph==2){ stageA(bufn,64,kn);  stageA(bufn,192,kn); }
    }
  };

  const int lr = lane&15;
  const int kq = lane>>4;
  const int axor = (lr&7)<<4;
  const int col0 = (kq<<4) ^ axor;          // K 0..63 half
  const int col1 = (64 | (kq<<4)) ^ axor;   // K 64..127 half
  const int arowb = (wm*128 + lr)*128;
  const int browb = ((VAR==0? wn*64 : wn*32) + lr)*128;

  i32x4 acc[8][NF];
  i32x4 acc2[(VAR==1)?8:1][NF];
  #pragma unroll
  for(int i=0;i<8;i++)
    #pragma unroll
    for(int j=0;j<NF;j++){ acc[i][j]=(i32x4){0,0,0,0}; if constexpr(VAR==1) acc2[i][j]=(i32x4){0,0,0,0}; }

  i32x4 breg[NF], breg2[(VAR==1)?NF:1];

  auto phase = [&](char* bufc, int ph, char* bufn, int kn, bool doStage){
    const int colb = (ph>>1)? col1 : col0;
    const int mh = ph&1;
    if(mh==0){
      #pragma unroll
      for(int nf=0;nf<NF;nf++)
        breg[nf] = *(const i32x4*)(bufc + 32768 + browb + nf*2048 + colb);
      if constexpr (VAR==1){
        #pragma unroll
        for(int nf=0;nf<NF;nf++)
          breg2[nf] = *(const i32x4*)(bufc + 32768 + 16384 + browb + nf*2048 + colb);
      }
    }
    i32x4 areg[4];
    #pragma unroll
    for(int i=0;i<4;i++)
      areg[i] = *(const i32x4*)(bufc + arowb + (mh*4+i)*2048 + colb);
    if(doStage) stagePh(ph, bufn, kn);
    __builtin_amdgcn_s_setprio(1);
    #pragma unroll
    for(int i=0;i<4;i++){
      #pragma unroll
      for(int nf=0;nf<NF;nf++){
        acc[mh*4+i][nf] = __builtin_amdgcn_mfma_i32_16x16x64_i8(areg[i], breg[nf], acc[mh*4+i][nf], 0,0,0);
        if constexpr (VAR==1)
          acc2[mh*4+i][nf] = __builtin_amdgcn_mfma_i32_16x16x64_i8(areg[i], breg2[nf], acc2[mh*4+i][nf], 0,0,0);
      }
    }
    __builtin_amdgcn_s_setprio(0);
  };

  #define VMW2 asm volatile("s_waitcnt vmcnt(2)" ::: "memory")
  #define VMW0 asm volatile("s_waitcnt vmcnt(0)" ::: "memory")
  #define BARR { __builtin_amdgcn_s_barrier(); __builtin_amdgcn_sched_barrier(0); }

  stagePh(0, lds, 0); stagePh(1, lds, 0); stagePh(2, lds, 0); stagePh(3, lds, 0);

  const int NT = K>>7;   // BK=128
  for(int t=0; t<NT-1; ++t){
    char* bufc = lds + (t&1)*TB;
    char* bufn = lds + ((t+1)&1)*TB;
    const int kn = (t+1)<<7;
    VMW2; BARR; phase(bufc, 0, bufn, kn, true);
    VMW2; BARR; phase(bufc, 1, bufn, kn, true);
          BARR; phase(bufc, 2, bufn, kn, true);
          BARR; phase(bufc, 3, bufn, kn, true);
  }
  {
    char* bufc = lds + ((NT-1)&1)*TB;
    VMW2; BARR; phase(bufc, 0, nullptr, 0, false);
    VMW0; BARR; phase(bufc, 1, nullptr, 0, false);
          BARR; phase(bufc, 2, nullptr, 0, false);
          BARR; phase(bufc, 3, nullptr, 0, false);
  }

  // ---- C write ----
  float sw;
  if constexpr (EPI==EPI_IFG) sw = p.swinv[(nb*256)>>10];
  else                        sw = *p.swinv;
  const int r0 = mb*256 + wm*128;
  const int c0 = nb*BN + wn*((VAR==0)?64:32);
  #pragma unroll
  for(int mf=0;mf<8;mf++){
    #pragma unroll
    for(int j=0;j<4;j++){
      int r = r0 + mf*16 + kq*4 + j;
      float rs = p.rsx[r]*sw;
      #pragma unroll
      for(int nf=0;nf<NF;nf++){
        int c = c0 + nf*16 + lr;
        float val = (float)acc[mf][nf][j]*rs;
        if constexpr (EPI==EPI_IFG){
          int mat = c >> 10;
          p.outb[(size_t)mat*9437184 + (size_t)r*1024 + (c&1023)] = f2bf(val);
        } else if constexpr (EPI==EPI_GLU){
          float v2 = (float)acc2[mf][nf][j]*rs;
          p.outb[(size_t)r*Ncols + c] = f2bf(val*sigm(val)*v2);
        } else if constexpr (EPI==EPI_RESID){
          int b = r >> p.bshift;
          size_t idx = (size_t)r*DM + c;
          p.outf[idx] = p.resid[idx] + p.egate[b*6144 + 5*1024 + c]*val;
        } else { // EPI_WO
          int b = r / SJ; int s = r - b*SJ;
          if (s < SCTX){
            size_t idx = ((size_t)b*SCTX + s)*DM + c;
            float ov = p.enc[idx] + p.ec[b*6144 + 2*1024 + c]*val;
            p.out_c[idx]  = ov;
            p.out_c2[idx] = ov;
          } else {
            size_t idx = ((size_t)b*SIMG + (s-SCTX))*DM + c;
            p.out_h[idx] = p.hid[idx] + p.eh[b*6144 + 2*1024 + c]*val;
          }
        }
      }
    }
  }
  #undef VMW2
  #undef VMW0
  #undef BARR
}

// ---------------- small split-K int8 GEMM (ctx down-proj), atomic f32 ----------------
__global__ __launch_bounds__(256, 2)
void gemm_ra8(const signed char* __restrict__ Aq, const signed char* __restrict__ Wq,
              int K, int lda, GemmP p){
  __shared__ signed char As[128*128];
  __shared__ signed char Bs[128*128];
  const int tid = threadIdx.x;
  const int wave = tid>>6, lane = tid&63;
  const int nwg = gridDim.x*gridDim.y;
  const int id  = blockIdx.y*gridDim.x + blockIdx.x;
  const int wg  = (id&7)*(nwg>>3) + (id>>3);
  const int nb  = wg % gridDim.x, mb = wg / gridDim.x;
  const int wr = wave>>1, wc = wave&1;
  const int koff = blockIdx.z*K;

  const int grow = wave*8 + (lane>>3);
  const int gcol = (lane&7)*16;
  const signed char* ag = Aq + (size_t)(mb*128 + grow)*lda + koff + gcol;
  const signed char* bg = Wq + (size_t)(nb*128 + grow)*lda + koff + gcol;
  char* asl = (char*)As + wave*1024;
  char* bsl = (char*)Bs + wave*1024;

  i32x4 acc[4][4];
  #pragma unroll
  for(int i=0;i<4;i++)
    #pragma unroll
    for(int j=0;j<4;j++) acc[i][j] = (i32x4){0,0,0,0};

  const int lrow = lane&15, kq = lane>>4;
  const signed char* arow = &As[(wr*64 + lrow)*128 + kq*16];
  const signed char* brow = &Bs[(wc*64 + lrow)*128 + kq*16];

  for(int k0=0; k0<K; k0+=128){
    #pragma unroll
    for(int pp=0;pp<4;pp++){
      gl_lds16(ag + (size_t)pp*32*lda + k0, asl + pp*4096);
      gl_lds16(bg + (size_t)pp*32*lda + k0, bsl + pp*4096);
    }
    __syncthreads();
    #pragma unroll
    for(int kk=0;kk<2;kk++){
      i32x4 af[4], bfr[4];
      #pragma unroll
      for(int m=0;m<4;m++) af[m]  = *(const i32x4*)(arow + m*2048 + kk*64);
      #pragma unroll
      for(int n=0;n<4;n++) bfr[n] = *(const i32x4*)(brow + n*2048 + kk*64);
      #pragma unroll
      for(int m=0;m<4;m++)
        #pragma unroll
        for(int n=0;n<4;n++)
          acc[m][n] = __builtin_amdgcn_mfma_i32_16x16x64_i8(af[m], bfr[n], acc[m][n], 0,0,0);
    }
    __syncthreads();
  }

  const float sw = *p.swinv;
  const int r0 = mb*128 + wr*64, c0 = nb*128 + wc*64;
  #pragma unroll
  for(int m=0;m<4;m++){
    #pragma unroll
    for(int j=0;j<4;j++){
      int r = r0 + m*16 + kq*4 + j;
      float rs = p.rsx[r]*sw;
      #pragma unroll
      for(int n=0;n<4;n++){
        int c = c0 + n*16 + lrow;
        float val = (float)acc[m][n][j]*rs;
        int b = r >> p.bshift;
        size_t idx = (size_t)r*DM + c;
        atomicAdd(&p.outf[idx], p.egate[b*6144 + 5*1024 + c]*val);
      }
    }
  }
}

// ================= host =================
extern "C" void kernel_launch(void* const* d_in, const int* in_sizes, int n_in,
                              void* d_out, int out_size, void* d_ws, size_t ws_size,
                              hipStream_t stream){
  (void)in_sizes; (void)n_in; (void)out_size; (void)ws_size;
  const float* hidden   = (const float*)d_in[0];
  const float* enc      = (const float*)d_in[1];
  const float* temb     = (const float*)d_in[2];
  const float* adaln_w  = (const float*)d_in[3];
  const float* adaln_b  = (const float*)d_in[4];
  const float* adaln_cw = (const float*)d_in[5];
  const float* adaln_cb = (const float*)d_in[6];
  const float* wi  = (const float*)d_in[7];
  const float* wf  = (const float*)d_in[8];
  const float* wg  = (const float*)d_in[9];
  const float* wo  = (const float*)d_in[10];
  const float* gnw = (const float*)d_in[11];
  const float* ffg = (const float*)d_in[12];
  const float* ffd = (const float*)d_in[13];
  const float* fcg = (const float*)d_in[14];
  const float* fcd = (const float*)d_in[15];

  const size_t MB = 1024ull*1024ull;
  char* ws = (char*)d_ws;
  signed char* W8_IFG = (signed char*)(ws + 0*MB);     // wi@0, wf@1MB, wg@2MB
  signed char* W8_WO  = (signed char*)(ws + 3*MB);
  signed char* W8_FFG = (signed char*)(ws + 4*MB);     // 8 MB (gate@0, val@+4M elems)
  signed char* W8_FFD = (signed char*)(ws + 12*MB);
  signed char* W8_FCG = (signed char*)(ws + 16*MB);
  signed char* W8_FCD = (signed char*)(ws + 24*MB);
  float* PART  = (float*)(ws + 28*MB);
  float* SWINV = (float*)(ws + 28*MB + 32*1024);
  float* EH    = (float*)(ws + 28*MB + 64*1024);
  float* EC    = (float*)(ws + 28*MB + 112*1024);
  float* RSX1  = (float*)(ws + 28*MB + 160*1024);
  float* RSX2  = (float*)(ws + 28*MB + 200*1024);
  float* RSX3  = (float*)(ws + 28*MB + 240*1024);
  float* RSXZ  = (float*)(ws + 28*MB + 280*1024);
  float* RSX4  = (float*)(ws + 28*MB + 320*1024);
  float* RSXZC = (float*)(ws + 28*MB + 328*1024);
  float* SCANA = (float*)(ws + 29*MB);
  float* SCANB = (float*)(ws + 33*MB);
  float* SCANH = (float*)(ws + 37*MB);
  signed char* XQ8 = (signed char*)(ws + 41*MB);          // 9.4 MB
  unsigned short* IRAW = (unsigned short*)(ws + 51*MB);   // 18 MB each
  unsigned short* FRAW = (unsigned short*)(ws + 69*MB);
  unsigned short* GRAW = (unsigned short*)(ws + 87*MB);
  unsigned short* OBUF = (unsigned short*)(ws + 105*MB);
  unsigned short* SGB  = (unsigned short*)(ws + 51*MB);   // 64 MB, overlays IRAW..OBUF (dead)
  signed char* SG8 = (signed char*)(ws + 115*MB);         // 32 MB
  float* HNEW = (float*)(ws + 147*MB);                    // 33.6 MB
  float* CNEW = (float*)(ws + 181*MB);                    // 4.2 MB
  float* OUT_H = (float*)d_out;
  float* OUT_C = (float*)d_out + 8388608;

  // ---- weight quantization ----
  WList L;
  L.w[0]=wi;  L.n[0]=1048576ull; L.q[0]=W8_IFG;
  L.w[1]=wf;  L.n[1]=1048576ull; L.q[1]=W8_IFG + 1048576;
  L.w[2]=wg;  L.n[2]=1048576ull; L.q[2]=W8_IFG + 2097152;
  L.w[3]=wo;  L.n[3]=1048576ull; L.q[3]=W8_WO;
  L.w[4]=ffg; L.n[4]=8388608ull; L.q[4]=W8_FFG;
  L.w[5]=ffd; L.n[5]=4194304ull; L.q[5]=W8_FFD;
  L.w[6]=fcg; L.n[6]=8388608ull; L.q[6]=W8_FCG;
  L.w[7]=fcd; L.n[7]=4194304ull; L.q[7]=W8_FCD;
  wq_reduce  <<<dim3(512,8), 256, 0, stream>>>(L, PART);
  wq_finalize<<<8,          256, 0, stream>>>(L, PART, SWINV);
  wq_quant   <<<dim3(1024,8),256, 0, stream>>>(L, SWINV);

  // ---- adaLN embeddings ----
  adaln_gemv<<<dim3(1536,2), 256, 0, stream>>>(temb, adaln_w,  adaln_b,  EH);
  adaln_gemv<<<dim3(1536,2), 256, 0, stream>>>(temb, adaln_cw, adaln_cb, EC);

  // ---- joint = [adaLN(enc); adaLN(hidden)], rmsnorm+quant (int8) ----
  modnorm_quant<<<1024, 256, 0, stream>>>(enc,    9,  EC, 0, 1024, XQ8, RSX1, 0,   SJ);
  modnorm_quant<<<8192, 256, 0, stream>>>(hidden, 12, EH, 0, 1024, XQ8, RSX1, 512, SJ);

  // ---- merged i/f/g bitlinear (N=3072), int8 8-phase ----
  GemmP p{};
  p.rsx = RSX1; p.swinv = SWINV; p.outb = IRAW;
  gemm8<0,EPI_IFG,0><<<dim3(12,36), 512, 0, stream>>>(XQ8, W8_IFG, 3072, 1024, 1024, p);

  // ---- HGRN scan ----
  scan_pass1<<<dim3(NCH,2), 256, 0, stream>>>(IRAW, FRAW, SCANA, SCANB);
  scan_pass2<<<8,           256, 0, stream>>>(SCANA, SCANB, SCANH);
  scan_pass3<<<dim3(NCH,2), 256, 0, stream>>>(IRAW, FRAW, SCANH, OBUF);

  // ---- gnorm + gate + quant ----
  gnorm_quant<<<9216, 256, 0, stream>>>(OBUF, GRAW, gnw, XQ8, RSX2);

  // ---- wo bitlinear with gated residual split (also pre-fills OUT_C) ----
  GemmP pw{};
  pw.rsx = RSX2; pw.swinv = SWINV+3;
  pw.eh = EH; pw.ec = EC; pw.hid = hidden; pw.enc = enc;
  pw.out_h = HNEW; pw.out_c = CNEW; pw.out_c2 = OUT_C;
  gemm8<2,EPI_WO,0><<<dim3(8,36), 512, 0, stream>>>(XQ8, W8_WO, 1024, 1024, 1024, pw);

  // ---- image MLP ----
  modnorm_quant<<<8192, 256, 0, stream>>>(HNEW, 12, EH, 3*1024, 4*1024, XQ8, RSX3, 0, SIMG);
  GemmP pg{};
  pg.rsx = RSX3; pg.swinv = SWINV+4; pg.outb = SGB; pg.w2 = W8_FFG + (size_t)4096*1024;
  gemm8<1,EPI_GLU,1><<<dim3(32,32), 512, 0, stream>>>(XQ8, W8_FFG, 4096, 1024, 1024, pg);
  rmsq4096<<<8192, 256, 0, stream>>>(SGB, SG8, RSXZ);
  GemmP pd{};
  pd.rsx = RSXZ; pd.swinv = SWINV+5; pd.outf = OUT_H; pd.resid = HNEW; pd.egate = EH; pd.bshift = 12;
  gemm8<2,EPI_RESID,0><<<dim3(8,32), 512, 0, stream>>>(SG8, W8_FFD, 1024, 4096, 4096, pd);

  // ---- context MLP ----
  modnorm_quant<<<1024, 256, 0, stream>>>(CNEW, 9, EC, 3*1024, 4*1024, XQ8, RSX4, 0, SCTX);
  GemmP pc{};
  pc.rsx = RSX4; pc.swinv = SWINV+6; pc.outb = SGB; pc.w2 = W8_FCG + (size_t)4096*1024;
  gemm8<1,EPI_GLU,1><<<dim3(32,4), 512, 0, stream>>>(XQ8, W8_FCG, 4096, 1024, 1024, pc);
  rmsq4096<<<1024, 256, 0, stream>>>(SGB, SG8, RSXZC);
  GemmP pe{};
  pe.rsx = RSXZC; pe.swinv = SWINV+7; pe.outf = OUT_C; pe.egate = EC; pe.bshift = 9;
  gemm_ra8<<<dim3(8,8,4), 256, 0, stream>>>(SG8, W8_FCD, 1024, 4096, pe);
}

// Round 5
// 465.363 us; speedup vs baseline: 2.0257x; 1.0989x over previous
//
#include <hip/hip_runtime.h>
#include <hip/hip_bf16.h>
#include <stdint.h>

#define DM   1024
#define SJ   4608
#define SCTX 512
#define SIMG 4096
#define NCH  512
#define TCH  9

typedef __attribute__((ext_vector_type(4))) int   i32x4;
typedef __attribute__((ext_vector_type(4))) float f32x4;

__device__ __forceinline__ float bf2f(unsigned short u){
  union { unsigned int i; float f; } v; v.i = ((unsigned int)u) << 16; return v.f;
}
__device__ __forceinline__ unsigned short f2bf(float f){
  unsigned int u = __float_as_uint(f);
  u += 0x7fffu + ((u >> 16) & 1u);
  return (unsigned short)(u >> 16);
}
__device__ __forceinline__ float sigm(float x){ return 1.f/(1.f+__expf(-x)); }
__device__ __forceinline__ signed char q8(float v, float lo, float hi){
  return (signed char)(int)fminf(fmaxf(rintf(v),lo),hi);
}

__device__ __forceinline__ float wsum(float v){
  #pragma unroll
  for(int o=32;o>0;o>>=1) v += __shfl_xor(v,o);
  return v;
}
__device__ __forceinline__ float wmax(float v){
  #pragma unroll
  for(int o=32;o>0;o>>=1) v = fmaxf(v,__shfl_xor(v,o));
  return v;
}
__device__ __forceinline__ void blockSumSum(float& a, float& b, float* s1, float* s2){
  a = wsum(a); b = wsum(b);
  if(!(threadIdx.x&63)){ s1[threadIdx.x>>6]=a; s2[threadIdx.x>>6]=b; }
  __syncthreads();
  a = s1[0]+s1[1]+s1[2]+s1[3];
  b = s2[0]+s2[1]+s2[2]+s2[3];
  __syncthreads();
}
__device__ __forceinline__ void blockSumMax(float& a, float& b, float* s1, float* s2){
  a = wsum(a); b = wmax(b);
  if(!(threadIdx.x&63)){ s1[threadIdx.x>>6]=a; s2[threadIdx.x>>6]=b; }
  __syncthreads();
  a = s1[0]+s1[1]+s1[2]+s1[3];
  b = fmaxf(fmaxf(s2[0],s2[1]),fmaxf(s2[2],s2[3]));
  __syncthreads();
}

// ---------------- async global->LDS ----------------
typedef __attribute__((address_space(1))) void gvoid_t;
typedef __attribute__((address_space(3))) void lvoid_t;
__device__ __forceinline__ void gl_lds16(const void* g, void* l){
  __builtin_amdgcn_global_load_lds((gvoid_t*)g, (lvoid_t*)l, 16, 0, 0);
}

// ---------------- weight quantization ----------------
struct WList {
  const float* w[8];
  unsigned long long n[8];
  signed char* q[8];
};

__global__ __launch_bounds__(256)
void wq_reduce(WList L, float* __restrict__ part){
  __shared__ float s1[4];
  int m = blockIdx.y;
  const float4* w4 = (const float4*)L.w[m];
  size_t n4 = L.n[m] >> 2;
  float s = 0.f;
  for(size_t i = (size_t)blockIdx.x*256 + threadIdx.x; i < n4; i += (size_t)512*256){
    float4 v = w4[i];
    s += fabsf(v.x)+fabsf(v.y)+fabsf(v.z)+fabsf(v.w);
  }
  s = wsum(s);
  if(!(threadIdx.x&63)) s1[threadIdx.x>>6] = s;
  __syncthreads();
  if(!threadIdx.x) part[m*512 + blockIdx.x] = s1[0]+s1[1]+s1[2]+s1[3];
}

__global__ __launch_bounds__(256)
void wq_finalize(WList L, const float* __restrict__ part, float* __restrict__ swinv){
  __shared__ float s1[4];
  int m = blockIdx.x;
  float s = part[m*512 + threadIdx.x] + part[m*512 + 256 + threadIdx.x];
  s = wsum(s);
  if(!(threadIdx.x&63)) s1[threadIdx.x>>6] = s;
  __syncthreads();
  if(!threadIdx.x){
    float mean = (s1[0]+s1[1]+s1[2]+s1[3]) / (float)L.n[m];
    swinv[m] = fmaxf(mean, 1e-5f);
  }
}

__global__ __launch_bounds__(256)
void wq_quant(WList L, const float* __restrict__ swinv){
  int m = blockIdx.y;
  float sc = 1.f / swinv[m];
  const float4* w4 = (const float4*)L.w[m];
  signed char* q = L.q[m];
  size_t n4 = L.n[m] >> 2;
  for(size_t i = (size_t)blockIdx.x*256 + threadIdx.x; i < n4; i += (size_t)1024*256){
    float4 v = w4[i];
    char4 o;
    o.x = q8(v.x*sc,-1.f,1.f);
    o.y = q8(v.y*sc,-1.f,1.f);
    o.z = q8(v.z*sc,-1.f,1.f);
    o.w = q8(v.w*sc,-1.f,1.f);
    ((char4*)q)[i] = o;
  }
}

// ---------------- adaLN embedding GEMV ----------------
__global__ __launch_bounds__(256)
void adaln_gemv(const float* __restrict__ temb, const float* __restrict__ W,
                const float* __restrict__ bias, float* __restrict__ e){
  int o = blockIdx.x*4 + (threadIdx.x>>6);
  int b = blockIdx.y;
  int lane = threadIdx.x & 63;
  const float4* t4 = (const float4*)(temb + b*DM);
  const float4* w4 = (const float4*)(W + (size_t)o*DM);
  float acc = 0.f;
  #pragma unroll
  for(int i=0;i<4;i++){
    float4 tv = t4[i*64+lane], wv = w4[i*64+lane];
    acc += (tv.x*sigm(tv.x))*wv.x + (tv.y*sigm(tv.y))*wv.y
         + (tv.z*sigm(tv.z))*wv.z + (tv.w*sigm(tv.w))*wv.w;
  }
  acc = wsum(acc);
  if(!lane) e[b*6144 + o] = acc + bias[o];
}

// ---------------- LN -> adaLN modulate -> rmsnorm -> act_quant (int8) ----------------
__global__ __launch_bounds__(256)
void modnorm_quant(const float* __restrict__ x, int bshift,
                   const float* __restrict__ e, int scaleOff, int shiftOff,
                   signed char* __restrict__ xq, float* __restrict__ rsx,
                   int outRowOff, int outBatchStride){
  __shared__ float s1[4], s2[4];
  const int tid = threadIdx.x;
  const int row = blockIdx.x;
  const int b = row >> bshift, s = row & ((1<<bshift)-1);
  float4 xv = ((const float4*)(x + (size_t)row*DM))[tid];
  float sum = xv.x+xv.y+xv.z+xv.w;
  float ss  = xv.x*xv.x+xv.y*xv.y+xv.z*xv.z+xv.w*xv.w;
  blockSumSum(sum, ss, s1, s2);
  float mu  = sum * (1.f/DM);
  float inv = rsqrtf(ss*(1.f/DM) - mu*mu + 1e-6f);
  float4 scv = ((const float4*)(e + b*6144 + scaleOff))[tid];
  float4 shv = ((const float4*)(e + b*6144 + shiftOff))[tid];
  float n0 = (xv.x-mu)*inv*(1.f+scv.x)+shv.x;
  float n1 = (xv.y-mu)*inv*(1.f+scv.y)+shv.y;
  float n2 = (xv.z-mu)*inv*(1.f+scv.z)+shv.z;
  float n3 = (xv.w-mu)*inv*(1.f+scv.w)+shv.w;
  float ss2 = n0*n0+n1*n1+n2*n2+n3*n3;
  float mx  = fmaxf(fmaxf(fabsf(n0),fabsf(n1)),fmaxf(fabsf(n2),fabsf(n3)));
  blockSumMax(ss2, mx, s1, s2);
  float rms   = rsqrtf(ss2*(1.f/DM) + 1e-6f);
  float amaxn = fmaxf(mx*rms, 1e-5f);
  float k     = rms*127.f/amaxn;
  int orow = b*outBatchStride + outRowOff + s;
  char4 q;
  q.x = q8(n0*k,-128.f,127.f);
  q.y = q8(n1*k,-128.f,127.f);
  q.z = q8(n2*k,-128.f,127.f);
  q.w = q8(n3*k,-128.f,127.f);
  ((char4*)(xq + (size_t)orow*DM))[tid] = q;
  if(!tid) rsx[orow] = amaxn*(1.f/127.f);
}

// ---- fused: hnew = x + gate*attn ; write hnew (1-2 dests) ; LN->mod->rmsnorm->quant ----
__global__ __launch_bounds__(256)
void resid_modnorm(const float* __restrict__ x, const unsigned short* __restrict__ attn,
                   int attnRowOff, int bshift,
                   const float* __restrict__ e,
                   float* __restrict__ hout,
                   signed char* __restrict__ xq, float* __restrict__ rsx){
  __shared__ float s1[4], s2[4];
  const int tid = threadIdx.x;
  const int row = blockIdx.x;
  const int b = row >> bshift, s = row & ((1<<bshift)-1);
  const int arow = b*SJ + attnRowOff + s;
  float4 xv = ((const float4*)(x + (size_t)row*DM))[tid];
  ushort4 av = ((const ushort4*)(attn + (size_t)arow*DM))[tid];
  float4 gv = ((const float4*)(e + b*6144 + 2*1024))[tid];
  float h0 = xv.x + gv.x*bf2f(av.x);
  float h1 = xv.y + gv.y*bf2f(av.y);
  float h2 = xv.z + gv.z*bf2f(av.z);
  float h3 = xv.w + gv.w*bf2f(av.w);
  ((float4*)(hout + (size_t)row*DM))[tid] = make_float4(h0,h1,h2,h3);
  float sum = h0+h1+h2+h3;
  float ss  = h0*h0+h1*h1+h2*h2+h3*h3;
  blockSumSum(sum, ss, s1, s2);
  float mu  = sum * (1.f/DM);
  float inv = rsqrtf(ss*(1.f/DM) - mu*mu + 1e-6f);
  float4 scv = ((const float4*)(e + b*6144 + 3*1024))[tid];
  float4 shv = ((const float4*)(e + b*6144 + 4*1024))[tid];
  float n0 = (h0-mu)*inv*(1.f+scv.x)+shv.x;
  float n1 = (h1-mu)*inv*(1.f+scv.y)+shv.y;
  float n2 = (h2-mu)*inv*(1.f+scv.z)+shv.z;
  float n3 = (h3-mu)*inv*(1.f+scv.w)+shv.w;
  float ss2 = n0*n0+n1*n1+n2*n2+n3*n3;
  float mx  = fmaxf(fmaxf(fabsf(n0),fabsf(n1)),fmaxf(fabsf(n2),fabsf(n3)));
  blockSumMax(ss2, mx, s1, s2);
  float rms   = rsqrtf(ss2*(1.f/DM) + 1e-6f);
  float amaxn = fmaxf(mx*rms, 1e-5f);
  float k     = rms*127.f/amaxn;
  char4 q;
  q.x = q8(n0*k,-128.f,127.f);
  q.y = q8(n1*k,-128.f,127.f);
  q.z = q8(n2*k,-128.f,127.f);
  q.w = q8(n3*k,-128.f,127.f);
  ((char4*)(xq + (size_t)row*DM))[tid] = q;
  if(!tid) rsx[row] = amaxn*(1.f/127.f);
}

// ---- out = hnew + gate(chunk5)*mlp ----
__global__ __launch_bounds__(256)
void resid_out(const float* __restrict__ hnew, const unsigned short* __restrict__ mlp,
               const float* __restrict__ e, int bshift, float* __restrict__ out){
  const int tid = threadIdx.x;
  const int row = blockIdx.x;
  const int b = row >> bshift;
  float4 hv = ((const float4*)(hnew + (size_t)row*DM))[tid];
  ushort4 mv = ((const ushort4*)(mlp + (size_t)row*DM))[tid];
  float4 gv = ((const float4*)(e + b*6144 + 5*1024))[tid];
  float4 o;
  o.x = hv.x + gv.x*bf2f(mv.x);
  o.y = hv.y + gv.y*bf2f(mv.y);
  o.z = hv.z + gv.z*bf2f(mv.z);
  o.w = hv.w + gv.w*bf2f(mv.w);
  ((float4*)(out + (size_t)row*DM))[tid] = o;
}

// ---------------- rmsnorm -> act_quant, bf16 D=4096 rows -> int8 ----------------
__global__ __launch_bounds__(256)
void rmsq4096(const unsigned short* __restrict__ z, signed char* __restrict__ zq,
              float* __restrict__ rsx){
  __shared__ float s1[4], s2[4];
  const int tid = threadIdx.x;
  const unsigned short* zr = z + (size_t)blockIdx.x*4096;
  signed char* qr = zq + (size_t)blockIdx.x*4096;
  float v[16];
  #pragma unroll
  for(int i=0;i<4;i++){
    ushort4 u = ((const ushort4*)zr)[tid + i*256];
    v[i*4+0]=bf2f(u.x); v[i*4+1]=bf2f(u.y); v[i*4+2]=bf2f(u.z); v[i*4+3]=bf2f(u.w);
  }
  float ss=0.f, mx=0.f;
  #pragma unroll
  for(int i=0;i<16;i++){ ss += v[i]*v[i]; mx = fmaxf(mx, fabsf(v[i])); }
  blockSumMax(ss, mx, s1, s2);
  float rms   = rsqrtf(ss*(1.f/4096.f) + 1e-6f);
  float amaxn = fmaxf(mx*rms, 1e-5f);
  float k     = rms*127.f/amaxn;
  #pragma unroll
  for(int i=0;i<4;i++){
    char4 q;
    q.x = q8(v[i*4+0]*k,-128.f,127.f);
    q.y = q8(v[i*4+1]*k,-128.f,127.f);
    q.z = q8(v[i*4+2]*k,-128.f,127.f);
    q.w = q8(v[i*4+3]*k,-128.f,127.f);
    ((char4*)qr)[tid + i*256] = q;
  }
  if(!tid) rsx[blockIdx.x] = amaxn*(1.f/127.f);
}

// ---------------- HGRN chunked scan ----------------
__global__ __launch_bounds__(256)
void scan_pass1(const unsigned short* __restrict__ ir, const unsigned short* __restrict__ fr,
                float* __restrict__ A, float* __restrict__ B){
  int c = blockIdx.x, b = blockIdx.y;
  int d0 = threadIdx.x*4;
  size_t base = ((size_t)b*SJ + (size_t)c*TCH)*DM + d0;
  float a0=1,a1=1,a2=1,a3=1, h0=0,h1=0,h2=0,h3=0;
  #pragma unroll
  for(int t=0;t<TCH;t++){
    ushort4 iv = *(const ushort4*)(ir + base + (size_t)t*DM);
    ushort4 fv = *(const ushort4*)(fr + base + (size_t)t*DM);
    float f0=sigm(bf2f(fv.x)), f1=sigm(bf2f(fv.y)), f2=sigm(bf2f(fv.z)), f3=sigm(bf2f(fv.w));
    float x0=bf2f(iv.x), x1=bf2f(iv.y), x2=bf2f(iv.z), x3=bf2f(iv.w);
    float p0=x0*sigm(x0)*(1.f-f0), p1=x1*sigm(x1)*(1.f-f1);
    float p2=x2*sigm(x2)*(1.f-f2), p3=x3*sigm(x3)*(1.f-f3);
    h0=f0*h0+p0; h1=f1*h1+p1; h2=f2*h2+p2; h3=f3*h3+p3;
    a0*=f0; a1*=f1; a2*=f2; a3*=f3;
  }
  size_t idx = (size_t)c*2048 + b*1024 + d0;
  *(float4*)(A + idx) = make_float4(a0,a1,a2,a3);
  *(float4*)(B + idx) = make_float4(h0,h1,h2,h3);
}

__global__ __launch_bounds__(256)
void scan_pass2(const float* __restrict__ A, const float* __restrict__ B, float* __restrict__ H){
  int chain = blockIdx.x*256 + threadIdx.x;
  float h = 0.f;
  for(int c0=0;c0<NCH;c0+=8){
    float a[8], bb[8];
    #pragma unroll
    for(int u=0;u<8;u++){
      a[u]  = A[(size_t)(c0+u)*2048 + chain];
      bb[u] = B[(size_t)(c0+u)*2048 + chain];
    }
    #pragma unroll
    for(int u=0;u<8;u++){
      H[(size_t)(c0+u)*2048 + chain] = h;
      h = a[u]*h + bb[u];
    }
  }
}

// ---- fused scan pass3 + gnorm + act_quant: o=scan(h); n=rmsnorm(o)*gnw*silu(g); quant ----
__global__ __launch_bounds__(256)
void scan3_gnorm(const unsigned short* __restrict__ ir, const unsigned short* __restrict__ fr,
                 const float* __restrict__ H, const unsigned short* __restrict__ g,
                 const float* __restrict__ gnw,
                 signed char* __restrict__ xq, float* __restrict__ rsx){
  __shared__ float s1[4], s2[4];
  int c = blockIdx.x, b = blockIdx.y;
  const int tid = threadIdx.x;
  int d0 = tid*4;
  size_t base = ((size_t)b*SJ + (size_t)c*TCH)*DM + d0;
  float4 hv = *(const float4*)(H + (size_t)c*2048 + b*1024 + d0);
  float h0=hv.x, h1=hv.y, h2=hv.z, h3=hv.w;
  float4 wv = ((const float4*)gnw)[tid];
  #pragma unroll
  for(int t=0;t<TCH;t++){
    ushort4 iv = *(const ushort4*)(ir + base + (size_t)t*DM);
    ushort4 fv = *(const ushort4*)(fr + base + (size_t)t*DM);
    float f0=sigm(bf2f(fv.x)), f1=sigm(bf2f(fv.y)), f2=sigm(bf2f(fv.z)), f3=sigm(bf2f(fv.w));
    float x0=bf2f(iv.x), x1=bf2f(iv.y), x2=bf2f(iv.z), x3=bf2f(iv.w);
    float p0=x0*sigm(x0)*(1.f-f0), p1=x1*sigm(x1)*(1.f-f1);
    float p2=x2*sigm(x2)*(1.f-f2), p3=x3*sigm(x3)*(1.f-f3);
    h0=f0*h0+p0; h1=f1*h1+p1; h2=f2*h2+p2; h3=f3*h3+p3;
    // gnorm on this row
    float ss = h0*h0+h1*h1+h2*h2+h3*h3, dummy = 0.f;
    blockSumSum(ss, dummy, s1, s2);
    float rms = rsqrtf(ss*(1.f/DM) + 1e-6f);
    ushort4 gv = *(const ushort4*)(g + base + (size_t)t*DM);
    float g0=bf2f(gv.x), g1=bf2f(gv.y), g2=bf2f(gv.z), g3=bf2f(gv.w);
    float n0 = h0*rms*wv.x*(g0*sigm(g0));
    float n1 = h1*rms*wv.y*(g1*sigm(g1));
    float n2 = h2*rms*wv.z*(g2*sigm(g2));
    float n3 = h3*rms*wv.w*(g3*sigm(g3));
    float ss2 = n0*n0+n1*n1+n2*n2+n3*n3;
    float mx  = fmaxf(fmaxf(fabsf(n0),fabsf(n1)),fmaxf(fabsf(n2),fabsf(n3)));
    blockSumMax(ss2, mx, s1, s2);
    float rms2  = rsqrtf(ss2*(1.f/DM) + 1e-6f);
    float amaxn = fmaxf(mx*rms2, 1e-5f);
    float k     = rms2*127.f/amaxn;
    char4 q;
    q.x = q8(n0*k,-128.f,127.f);
    q.y = q8(n1*k,-128.f,127.f);
    q.z = q8(n2*k,-128.f,127.f);
    q.w = q8(n3*k,-128.f,127.f);
    size_t row = (size_t)b*SJ + (size_t)c*TCH + t;
    *(char4*)(xq + row*DM + d0) = q;
    if(!tid) rsx[row] = amaxn*(1.f/127.f);
  }
}

// ---------------- epilogue ids ----------------
#define EPI_IFG    0
#define EPI_OUT    1
#define EPI_GLU    2

struct GemmP {
  const float* rsx;
  const float* swinv;
  unsigned short* outb;
  float* outf;
  const float* egate;
  int bshift;
  const signed char* w2;
};

// ================== 8-phase 256-row pipelined int8 GEMM, BK=128 ==================
// VAR 0: BN=256 single-B | VAR 1: BN=128 dual-B (fused GLU) | VAR 2: BN=128 single-B
// SWZ 0: row-chunked XCD swizzle | SWZ 1: column-chunked (gx must be 32; 4 nb per XCD)
template<int VAR, int EPI, int SWZ>
__global__ __launch_bounds__(512, 2)
void gemm8(const signed char* __restrict__ Aq, const signed char* __restrict__ Bq,
           int Ncols, int K, int lda, GemmP p){
  constexpr int BBYT = (VAR==2)? 16384 : 32768;
  constexpr int TB   = 32768 + BBYT;
  constexpr int NF   = (VAR==0)? 4 : 2;
  constexpr int BN   = (VAR==0)? 256 : 128;
  __shared__ char lds[2*TB];

  const int tid = threadIdx.x, wv = tid>>6, lane = tid&63;
  const int wm = wv>>2, wn = wv&3;
  const int nwg = gridDim.x*gridDim.y;
  const int id  = blockIdx.y*gridDim.x + blockIdx.x;
  int nb, mb;
  if constexpr (SWZ==1){
    const int x = id&7, j = id>>3;
    nb = x*4 + (j&3);
    mb = j>>2;
  } else {
    const int wg = (id&7)*(nwg>>3) + (id>>3);
    nb = wg % gridDim.x; mb = wg / gridDim.x;
  }

  const int srow = wv*8 + (lane>>3);
  const int sch  = ((lane&7) ^ (lane>>3))*16;
  const signed char* ag  = Aq + (size_t)(mb*256 + srow)*lda + sch;
  const signed char* bg1 = Bq + (size_t)(nb*BN  + srow)*lda + sch;
  const signed char* bg2 = nullptr;
  if constexpr (VAR==1) bg2 = p.w2 + (size_t)(nb*128 + srow)*lda + sch;
  const int wvoff = wv*1024;

  auto stageA = [&](char* bufn, int rb, int k0){
    gl_lds16(ag + (size_t)rb*lda + k0, bufn + rb*128 + wvoff);
  };
  auto stageB = [&](char* bufn, int rb, int k0, int m2){
    const signed char* src = m2 ? bg2 : bg1;
    gl_lds16(src + (size_t)rb*lda + k0, bufn + 32768 + m2*16384 + rb*128 + wvoff);
  };
  auto stagePh = [&](int ph, char* bufn, int kn){
    if constexpr (VAR==0){
      if(ph==0){ stageB(bufn,0,kn,0);   stageB(bufn,64,kn,0); }
      else if(ph==1){ stageB(bufn,128,kn,0); stageB(bufn,192,kn,0); }
      else if(ph==2){ stageA(bufn,0,kn);   stageA(bufn,128,kn); }
      else          { stageA(bufn,64,kn);  stageA(bufn,192,kn); }
    } else if constexpr (VAR==1){
      if(ph==0){ stageB(bufn,0,kn,0);  stageB(bufn,64,kn,0); }
      else if(ph==1){ stageB(bufn,0,kn,1);  stageB(bufn,64,kn,1); }
      else if(ph==2){ stageA(bufn,0,kn);   stageA(bufn,128,kn); }
      else          { stageA(bufn,64,kn);  stageA(bufn,192,kn); }
    } else {
      if(ph==0){ stageB(bufn,0,kn,0);  stageB(bufn,64,kn,0); }
      else if(ph==1){ stageA(bufn,0,kn);   stageA(bufn,128,kn); }
      else if(ph==2){ stageA(bufn,64,kn);  stageA(bufn,192,kn); }
    }
  };

  const int lr = lane&15;
  const int kq = lane>>4;
  const int axor = (lr&7)<<4;
  const int col0 = (kq<<4) ^ axor;
  const int col1 = (64 | (kq<<4)) ^ axor;
  const int arowb = (wm*128 + lr)*128;
  const int browb = ((VAR==0? wn*64 : wn*32) + lr)*128;

  i32x4 acc[8][NF];
  i32x4 acc2[(VAR==1)?8:1][NF];
  #pragma unroll
  for(int i=0;i<8;i++)
    #pragma unroll
    for(int j=0;j<NF;j++){ acc[i][j]=(i32x4){0,0,0,0}; if constexpr(VAR==1) acc2[i][j]=(i32x4){0,0,0,0}; }

  i32x4 breg[NF], breg2[(VAR==1)?NF:1];

  auto phase = [&](char* bufc, int ph, char* bufn, int kn, bool doStage){
    const int colb = (ph>>1)? col1 : col0;
    const int mh = ph&1;
    if(mh==0){
      #pragma unroll
      for(int nf=0;nf<NF;nf++)
        breg[nf] = *(const i32x4*)(bufc + 32768 + browb + nf*2048 + colb);
      if constexpr (VAR==1){
        #pragma unroll
        for(int nf=0;nf<NF;nf++)
          breg2[nf] = *(const i32x4*)(bufc + 32768 + 16384 + browb + nf*2048 + colb);
      }
    }
    i32x4 areg[4];
    #pragma unroll
    for(int i=0;i<4;i++)
      areg[i] = *(const i32x4*)(bufc + arowb + (mh*4+i)*2048 + colb);
    if(doStage) stagePh(ph, bufn, kn);
    __builtin_amdgcn_s_setprio(1);
    #pragma unroll
    for(int i=0;i<4;i++){
      #pragma unroll
      for(int nf=0;nf<NF;nf++){
        acc[mh*4+i][nf] = __builtin_amdgcn_mfma_i32_16x16x64_i8(areg[i], breg[nf], acc[mh*4+i][nf], 0,0,0);
        if constexpr (VAR==1)
          acc2[mh*4+i][nf] = __builtin_amdgcn_mfma_i32_16x16x64_i8(areg[i], breg2[nf], acc2[mh*4+i][nf], 0,0,0);
      }
    }
    __builtin_amdgcn_s_setprio(0);
  };

  #define VMW2 asm volatile("s_waitcnt vmcnt(2)" ::: "memory")
  #define VMW0 asm volatile("s_waitcnt vmcnt(0)" ::: "memory")
  #define BARR { __builtin_amdgcn_s_barrier(); __builtin_amdgcn_sched_barrier(0); }

  stagePh(0, lds, 0); stagePh(1, lds, 0); stagePh(2, lds, 0); stagePh(3, lds, 0);

  const int NT = K>>7;
  for(int t=0; t<NT-1; ++t){
    char* bufc = lds + (t&1)*TB;
    char* bufn = lds + ((t+1)&1)*TB;
    const int kn = (t+1)<<7;
    VMW2; BARR; phase(bufc, 0, bufn, kn, true);
    VMW2; BARR; phase(bufc, 1, bufn, kn, true);
          BARR; phase(bufc, 2, bufn, kn, true);
          BARR; phase(bufc, 3, bufn, kn, true);
  }
  {
    char* bufc = lds + ((NT-1)&1)*TB;
    VMW2; BARR; phase(bufc, 0, nullptr, 0, false);
    VMW0; BARR; phase(bufc, 1, nullptr, 0, false);
          BARR; phase(bufc, 2, nullptr, 0, false);
          BARR; phase(bufc, 3, nullptr, 0, false);
  }

  // ---- C write ----
  float sw;
  if constexpr (EPI==EPI_IFG) sw = p.swinv[(nb*256)>>10];
  else                        sw = *p.swinv;
  const int r0 = mb*256 + wm*128;
  const int c0 = nb*BN + wn*((VAR==0)?64:32);
  #pragma unroll
  for(int mf=0;mf<8;mf++){
    #pragma unroll
    for(int j=0;j<4;j++){
      int r = r0 + mf*16 + kq*4 + j;
      float rs = p.rsx[r]*sw;
      #pragma unroll
      for(int nf=0;nf<NF;nf++){
        int c = c0 + nf*16 + lr;
        float val = (float)acc[mf][nf][j]*rs;
        if constexpr (EPI==EPI_IFG){
          int mat = c >> 10;
          p.outb[(size_t)mat*9437184 + (size_t)r*1024 + (c&1023)] = f2bf(val);
        } else if constexpr (EPI==EPI_GLU){
          float v2 = (float)acc2[mf][nf][j]*rs;
          p.outb[(size_t)r*Ncols + c] = f2bf(val*sigm(val)*v2);
        } else { // EPI_OUT
          p.outb[(size_t)r*Ncols + c] = f2bf(val);
        }
      }
    }
  }
  #undef VMW2
  #undef VMW0
  #undef BARR
}

// ---------------- small split-K int8 GEMM (ctx down-proj), atomic f32 ----------------
__global__ __launch_bounds__(256, 2)
void gemm_ra8(const signed char* __restrict__ Aq, const signed char* __restrict__ Wq,
              int K, int lda, GemmP p){
  __shared__ signed char As[128*128];
  __shared__ signed char Bs[128*128];
  const int tid = threadIdx.x;
  const int wave = tid>>6, lane = tid&63;
  const int nwg = gridDim.x*gridDim.y;
  const int id  = blockIdx.y*gridDim.x + blockIdx.x;
  const int wg  = (id&7)*(nwg>>3) + (id>>3);
  const int nb  = wg % gridDim.x, mb = wg / gridDim.x;
  const int wr = wave>>1, wc = wave&1;
  const int koff = blockIdx.z*K;

  const int grow = wave*8 + (lane>>3);
  const int gcol = (lane&7)*16;
  const signed char* ag = Aq + (size_t)(mb*128 + grow)*lda + koff + gcol;
  const signed char* bg = Wq + (size_t)(nb*128 + grow)*lda + koff + gcol;
  char* asl = (char*)As + wave*1024;
  char* bsl = (char*)Bs + wave*1024;

  i32x4 acc[4][4];
  #pragma unroll
  for(int i=0;i<4;i++)
    #pragma unroll
    for(int j=0;j<4;j++) acc[i][j] = (i32x4){0,0,0,0};

  const int lrow = lane&15, kq = lane>>4;
  const signed char* arow = &As[(wr*64 + lrow)*128 + kq*16];
  const signed char* brow = &Bs[(wc*64 + lrow)*128 + kq*16];

  for(int k0=0; k0<K; k0+=128){
    #pragma unroll
    for(int pp=0;pp<4;pp++){
      gl_lds16(ag + (size_t)pp*32*lda + k0, asl + pp*4096);
      gl_lds16(bg + (size_t)pp*32*lda + k0, bsl + pp*4096);
    }
    __syncthreads();
    #pragma unroll
    for(int kk=0;kk<2;kk++){
      i32x4 af[4], bfr[4];
      #pragma unroll
      for(int m=0;m<4;m++) af[m]  = *(const i32x4*)(arow + m*2048 + kk*64);
      #pragma unroll
      for(int n=0;n<4;n++) bfr[n] = *(const i32x4*)(brow + n*2048 + kk*64);
      #pragma unroll
      for(int m=0;m<4;m++)
        #pragma unroll
        for(int n=0;n<4;n++)
          acc[m][n] = __builtin_amdgcn_mfma_i32_16x16x64_i8(af[m], bfr[n], acc[m][n], 0,0,0);
    }
    __syncthreads();
  }

  const float sw = *p.swinv;
  const int r0 = mb*128 + wr*64, c0 = nb*128 + wc*64;
  #pragma unroll
  for(int m=0;m<4;m++){
    #pragma unroll
    for(int j=0;j<4;j++){
      int r = r0 + m*16 + kq*4 + j;
      float rs = p.rsx[r]*sw;
      #pragma unroll
      for(int n=0;n<4;n++){
        int c = c0 + n*16 + lrow;
        float val = (float)acc[m][n][j]*rs;
        int b = r >> p.bshift;
        size_t idx = (size_t)r*DM + c;
        atomicAdd(&p.outf[idx], p.egate[b*6144 + 5*1024 + c]*val);
      }
    }
  }
}

// ================= host =================
extern "C" void kernel_launch(void* const* d_in, const int* in_sizes, int n_in,
                              void* d_out, int out_size, void* d_ws, size_t ws_size,
                              hipStream_t stream){
  (void)in_sizes; (void)n_in; (void)out_size; (void)ws_size;
  const float* hidden   = (const float*)d_in[0];
  const float* enc      = (const float*)d_in[1];
  const float* temb     = (const float*)d_in[2];
  const float* adaln_w  = (const float*)d_in[3];
  const float* adaln_b  = (const float*)d_in[4];
  const float* adaln_cw = (const float*)d_in[5];
  const float* adaln_cb = (const float*)d_in[6];
  const float* wi  = (const float*)d_in[7];
  const float* wf  = (const float*)d_in[8];
  const float* wg  = (const float*)d_in[9];
  const float* wo  = (const float*)d_in[10];
  const float* gnw = (const float*)d_in[11];
  const float* ffg = (const float*)d_in[12];
  const float* ffd = (const float*)d_in[13];
  const float* fcg = (const float*)d_in[14];
  const float* fcd = (const float*)d_in[15];

  const size_t MB = 1024ull*1024ull;
  char* ws = (char*)d_ws;
  signed char* W8_IFG = (signed char*)(ws + 0*MB);
  signed char* W8_WO  = (signed char*)(ws + 3*MB);
  signed char* W8_FFG = (signed char*)(ws + 4*MB);
  signed char* W8_FFD = (signed char*)(ws + 12*MB);
  signed char* W8_FCG = (signed char*)(ws + 16*MB);
  signed char* W8_FCD = (signed char*)(ws + 24*MB);
  float* PART  = (float*)(ws + 28*MB);
  float* SWINV = (float*)(ws + 28*MB + 32*1024);
  float* EH    = (float*)(ws + 28*MB + 64*1024);
  float* EC    = (float*)(ws + 28*MB + 112*1024);
  float* RSX1  = (float*)(ws + 28*MB + 160*1024);
  float* RSX2  = (float*)(ws + 28*MB + 200*1024);
  float* RSX3  = (float*)(ws + 28*MB + 240*1024);
  float* RSXZ  = (float*)(ws + 28*MB + 280*1024);
  float* RSX4  = (float*)(ws + 28*MB + 320*1024);
  float* RSXZC = (float*)(ws + 28*MB + 328*1024);
  float* SCANA = (float*)(ws + 29*MB);
  float* SCANB = (float*)(ws + 33*MB);
  float* SCANH = (float*)(ws + 37*MB);
  signed char* XQ8 = (signed char*)(ws + 41*MB);           // 9.4 MB (joint; ctx MLP at rows 8192+)
  unsigned short* IRAW = (unsigned short*)(ws + 51*MB);    // 18 MB each
  unsigned short* FRAW = (unsigned short*)(ws + 69*MB);
  unsigned short* GRAW = (unsigned short*)(ws + 87*MB);
  unsigned short* ATTN = (unsigned short*)(ws + 51*MB);    // overlays IRAW (dead after scan3)
  signed char* SG8 = (signed char*)(ws + 51*MB);           // 32 MB, overlays ATTN (dead) later
  unsigned short* MLPH = (unsigned short*)(ws + 83*MB);    // 16 MB, overlays GRAW (dead)
  float* HNEW = (float*)(ws + 105*MB);                     // 32 MB
  unsigned short* SGB = (unsigned short*)(ws + 137*MB);    // 64 MB
  float* OUT_H = (float*)d_out;
  float* OUT_C = (float*)d_out + 8388608;

  // ---- weight quantization ----
  WList L;
  L.w[0]=wi;  L.n[0]=1048576ull; L.q[0]=W8_IFG;
  L.w[1]=wf;  L.n[1]=1048576ull; L.q[1]=W8_IFG + 1048576;
  L.w[2]=wg;  L.n[2]=1048576ull; L.q[2]=W8_IFG + 2097152;
  L.w[3]=wo;  L.n[3]=1048576ull; L.q[3]=W8_WO;
  L.w[4]=ffg; L.n[4]=8388608ull; L.q[4]=W8_FFG;
  L.w[5]=ffd; L.n[5]=4194304ull; L.q[5]=W8_FFD;
  L.w[6]=fcg; L.n[6]=8388608ull; L.q[6]=W8_FCG;
  L.w[7]=fcd; L.n[7]=4194304ull; L.q[7]=W8_FCD;
  wq_reduce  <<<dim3(512,8), 256, 0, stream>>>(L, PART);
  wq_finalize<<<8,          256, 0, stream>>>(L, PART, SWINV);
  wq_quant   <<<dim3(1024,8),256, 0, stream>>>(L, SWINV);

  // ---- adaLN embeddings ----
  adaln_gemv<<<dim3(1536,2), 256, 0, stream>>>(temb, adaln_w,  adaln_b,  EH);
  adaln_gemv<<<dim3(1536,2), 256, 0, stream>>>(temb, adaln_cw, adaln_cb, EC);

  // ---- joint = [adaLN(enc); adaLN(hidden)], rmsnorm+quant (int8) ----
  modnorm_quant<<<1024, 256, 0, stream>>>(enc,    9,  EC, 0, 1024, XQ8, RSX1, 0,   SJ);
  modnorm_quant<<<8192, 256, 0, stream>>>(hidden, 12, EH, 0, 1024, XQ8, RSX1, 512, SJ);

  // ---- merged i/f/g bitlinear (N=3072), int8 8-phase ----
  GemmP p{};
  p.rsx = RSX1; p.swinv = SWINV; p.outb = IRAW;
  gemm8<0,EPI_IFG,0><<<dim3(12,36), 512, 0, stream>>>(XQ8, W8_IFG, 3072, 1024, 1024, p);

  // ---- HGRN scan + fused gnorm/quant ----
  scan_pass1<<<dim3(NCH,2), 256, 0, stream>>>(IRAW, FRAW, SCANA, SCANB);
  scan_pass2<<<8,           256, 0, stream>>>(SCANA, SCANB, SCANH);
  scan3_gnorm<<<dim3(NCH,2), 256, 0, stream>>>(IRAW, FRAW, SCANH, GRAW, gnw, XQ8, RSX2);

  // ---- wo bitlinear -> bf16 ATTN (no epilogue traffic) ----
  GemmP pw{};
  pw.rsx = RSX2; pw.swinv = SWINV+3; pw.outb = ATTN;
  gemm8<2,EPI_OUT,0><<<dim3(8,36), 512, 0, stream>>>(XQ8, W8_WO, 1024, 1024, 1024, pw);

  // ---- fused residual + LN/mod/rmsnorm/quant (streaming, full occupancy) ----
  resid_modnorm<<<8192, 256, 0, stream>>>(hidden, ATTN, 512, 12, EH, HNEW, XQ8, RSX3);
  resid_modnorm<<<1024, 256, 0, stream>>>(enc,    ATTN, 0,   9,  EC, OUT_C,
                                          XQ8 + (size_t)8192*1024, RSX4);

  // ---- image MLP ----
  GemmP pg{};
  pg.rsx = RSX3; pg.swinv = SWINV+4; pg.outb = SGB; pg.w2 = W8_FFG + (size_t)4096*1024;
  gemm8<1,EPI_GLU,1><<<dim3(32,32), 512, 0, stream>>>(XQ8, W8_FFG, 4096, 1024, 1024, pg);
  rmsq4096<<<8192, 256, 0, stream>>>(SGB, SG8, RSXZ);
  GemmP pd{};
  pd.rsx = RSXZ; pd.swinv = SWINV+5; pd.outb = MLPH;
  gemm8<2,EPI_OUT,0><<<dim3(8,32), 512, 0, stream>>>(SG8, W8_FFD, 1024, 4096, 4096, pd);
  resid_out<<<8192, 256, 0, stream>>>(HNEW, MLPH, EH, 12, OUT_H);

  // ---- context MLP ----
  GemmP pc{};
  pc.rsx = RSX4; pc.swinv = SWINV+6; pc.outb = SGB; pc.w2 = W8_FCG + (size_t)4096*1024;
  gemm8<1,EPI_GLU,1><<<dim3(32,4), 512, 0, stream>>>(XQ8 + (size_t)8192*1024, W8_FCG, 4096, 1024, 1024, pc);
  rmsq4096<<<1024, 256, 0, stream>>>(SGB, SG8, RSXZC);
  GemmP pe{};
  pe.rsx = RSXZC; pe.swinv = SWINV+7; pe.outf = OUT_C; pe.egate = EC; pe.bshift = 9;
  gemm_ra8<<<dim3(8,8,4), 256, 0, stream>>>(SG8, W8_FCD, 1024, 4096, pe);
}